// Round 3
// baseline (460.016 us; speedup 1.0000x reference)
//
#include <hip/hip_runtime.h>
#include <hip/hip_bf16.h>
#include <math.h>

typedef __bf16 bf16x8 __attribute__((ext_vector_type(8)));
typedef float f32x4 __attribute__((ext_vector_type(4)));

#define SEQ 1500
#define CDIM 1280
#define NHEAD 20
#define DHEAD 64
#define NMLP 5120
#define QKVN 3840
#define VTLD 1504   // leading dim of transposed V (47*32)
#define APAD 68     // attention LDS stride

#define GLOAD_LDS16(gp, lp)                                                    \
  __builtin_amdgcn_global_load_lds(                                            \
      (const __attribute__((address_space(1))) unsigned int*)(gp),             \
      (__attribute__((address_space(3))) unsigned int*)(lp), 16, 0, 0)

// ---------------- pack params; each block self-detects dtype ----------------
// layout: [0,3840) qkvbias (bq|0|bv) | 3840 bo | 5120 g1 | 6400 be1 |
//         7680 g2 | 8960 be2 | 10240 b1(5120) | 15360 b2
__global__ __launch_bounds__(256) void pack_params_kernel(
    const unsigned int* __restrict__ xw, const void* bq, const void* bv,
    const void* bo, const void* g1, const void* be1, const void* g2,
    const void* be2, const void* b1, const void* b2,
    __bf16* __restrict__ pb, int* __restrict__ flag) {
  __shared__ int cnt[256];
  const unsigned int w = xw[threadIdx.x];
  const unsigned int e = (w >> 7) & 0xFF;
  cnt[threadIdx.x] = (e >= 100 && e <= 150) ? 1 : 0;
  __syncthreads();
  for (int s = 128; s > 0; s >>= 1) {
    if (threadIdx.x < (unsigned)s) cnt[threadIdx.x] += cnt[threadIdx.x + s];
    __syncthreads();
  }
  const int isbf = (cnt[0] >= 160) ? 1 : 0;
  if (blockIdx.x == 0 && threadIdx.x == 0) flag[0] = isbf;
  const int i = blockIdx.x * 256 + threadIdx.x;
  if (i >= 16640) return;
  auto ld = [&](const void* p, int j) -> float {
    return isbf ? (float)((const __bf16*)p)[j] : ((const float*)p)[j];
  };
  float v;
  if (i < 3840) {
    if (i < 1280) v = ld(bq, i);
    else if (i < 2560) v = 0.f;
    else v = ld(bv, i - 2560);
  } else if (i < 5120) v = ld(bo, i - 3840);
  else if (i < 6400) v = ld(g1, i - 5120);
  else if (i < 7680) v = ld(be1, i - 6400);
  else if (i < 8960) v = ld(g2, i - 7680);
  else if (i < 10240) v = ld(be2, i - 8960);
  else if (i < 15360) v = ld(b1, i - 10240);
  else v = ld(b2, i - 15360);
  pb[i] = (__bf16)v;
}

// ---------------- fused weight transpose: all 6 weights, one launch --------
// out layout: plain (N,K) row-major (strided reads spread HBM channels - R8)
__device__ __forceinline__ void transpose_body(const void* in, __bf16* out,
                                               int K, int N, int isbf,
                                               int bx, int by) {
  __shared__ __bf16 t[32][33];
  const int tx = threadIdx.x, ty = threadIdx.y;
  const int n0 = bx * 32, k0 = by * 32;
  if (isbf) {
    const __bf16* s = (const __bf16*)in;
#pragma unroll
    for (int i = ty; i < 32; i += 8)
      t[i][tx] = s[(size_t)(k0 + i) * N + n0 + tx];
  } else {
    const float* s = (const float*)in;
#pragma unroll
    for (int i = ty; i < 32; i += 8)
      t[i][tx] = (__bf16)s[(size_t)(k0 + i) * N + n0 + tx];
  }
  __syncthreads();
#pragma unroll
  for (int i = ty; i < 32; i += 8)
    out[(size_t)(n0 + i) * K + k0 + tx] = t[tx][i];
}

__global__ __launch_bounds__(256) void transpose_all_kernel(
    const void* Wq, const void* Wk, const void* Wv, const void* Wo,
    const void* W1, const void* W2, __bf16* __restrict__ Wqkvt,
    __bf16* __restrict__ Wot, __bf16* __restrict__ W1t,
    __bf16* __restrict__ W2t, const int* __restrict__ flag) {
  const int id = blockIdx.x;
  const int isbf = flag[0];
  if (id < 6400) {                      // Wq|Wk|Wv|Wo : 4 x (40x40)
    const int w = id / 1600, r = id % 1600;
    const void* in = (w == 0) ? Wq : (w == 1) ? Wk : (w == 2) ? Wv : Wo;
    __bf16* out = (w < 3) ? (Wqkvt + (size_t)w * CDIM * CDIM) : Wot;
    transpose_body(in, out, CDIM, CDIM, isbf, r % 40, r / 40);
  } else if (id < 12800) {              // W1 : 160x40
    const int r = id - 6400;
    transpose_body(W1, W1t, CDIM, NMLP, isbf, r % 160, r / 160);
  } else {                              // W2 : 40x160
    const int r = id - 12800;
    transpose_body(W2, W2t, NMLP, CDIM, isbf, r % 40, r / 40);
  }
}

// ---------------- activation transpose: [SEQ][.] -> [N][VTLD] --------------
__global__ __launch_bounds__(256) void transpose_act_kernel(const __bf16* __restrict__ in,
                                                            __bf16* __restrict__ out,
                                                            int istride) {
  __shared__ __bf16 t[32][33];
  const int tx = threadIdx.x, ty = threadIdx.y;
  const int n0 = blockIdx.x * 32, k0 = blockIdx.y * 32;
#pragma unroll
  for (int i = ty; i < 32; i += 8) {
    const int k = k0 + i;
    t[i][tx] = (k < SEQ) ? in[(size_t)k * istride + n0 + tx] : (__bf16)0.f;
  }
  __syncthreads();
#pragma unroll
  for (int i = ty; i < 32; i += 8) {
    const int kk = k0 + tx;
    if (kk < VTLD) out[(size_t)(n0 + i) * VTLD + kk] = t[tx][i];
  }
}

// ---------------- layernorm 1 (row-major out); X dtype per flag ------------
__global__ __launch_bounds__(256) void ln_kernel(const void* __restrict__ X,
                                                 const __bf16* __restrict__ gamma,
                                                 const __bf16* __restrict__ beta,
                                                 __bf16* __restrict__ Y,
                                                 const int* __restrict__ flag) {
  const int isf32 = (flag[0] == 0);
  const int row = blockIdx.x;
  float v[5];
  float s = 0.f, s2 = 0.f;
#pragma unroll
  for (int i = 0; i < 5; ++i) {
    const int c = threadIdx.x + 256 * i;
    const size_t idx = (size_t)row * CDIM + c;
    v[i] = isf32 ? ((const float*)X)[idx] : (float)((const __bf16*)X)[idx];
    s += v[i];
    s2 += v[i] * v[i];
  }
  const int lane = threadIdx.x & 63, wv = threadIdx.x >> 6;
#pragma unroll
  for (int off = 32; off > 0; off >>= 1) {
    s += __shfl_down(s, off);
    s2 += __shfl_down(s2, off);
  }
  __shared__ float red[8];
  if (lane == 0) { red[wv] = s; red[4 + wv] = s2; }
  __syncthreads();
  s = red[0] + red[1] + red[2] + red[3];
  s2 = red[4] + red[5] + red[6] + red[7];
  const float mu = s * (1.f / CDIM);
  const float var = s2 * (1.f / CDIM) - mu * mu;
  const float rstd = rsqrtf(fmaxf(var, 0.f) + 1e-5f);
#pragma unroll
  for (int i = 0; i < 5; ++i) {
    const int c = threadIdx.x + 256 * i;
    Y[(size_t)row * CDIM + c] =
        (__bf16)((v[i] - mu) * rstd * (float)gamma[c] + (float)beta[c]);
  }
}

// ---------------- fused: x1 = x + sum(P) + bo ; h2 = LN2(x1) ----------------
__global__ __launch_bounds__(256) void resid_ln_kernel(
    const float* __restrict__ P, const __bf16* __restrict__ bo,
    const void* __restrict__ X, const __bf16* __restrict__ gamma,
    const __bf16* __restrict__ beta, __bf16* __restrict__ X1,
    __bf16* __restrict__ H2, const int* __restrict__ flag) {
  const int isf32 = (flag[0] == 0);
  const int row = blockIdx.x;
  const int MN = SEQ * CDIM;
  float v[5];
  float s = 0.f, s2 = 0.f;
#pragma unroll
  for (int i = 0; i < 5; ++i) {
    const int c = threadIdx.x + 256 * i;
    const size_t idx = (size_t)row * CDIM + c;
    const float xv = isf32 ? ((const float*)X)[idx] : (float)((const __bf16*)X)[idx];
    const float val = P[idx] + P[MN + idx] + (float)bo[c] + xv;
    X1[idx] = (__bf16)val;
    v[i] = val;
    s += val;
    s2 += val * val;
  }
  const int lane = threadIdx.x & 63, wv = threadIdx.x >> 6;
#pragma unroll
  for (int off = 32; off > 0; off >>= 1) {
    s += __shfl_down(s, off);
    s2 += __shfl_down(s2, off);
  }
  __shared__ float red[8];
  if (lane == 0) { red[wv] = s; red[4 + wv] = s2; }
  __syncthreads();
  s = red[0] + red[1] + red[2] + red[3];
  s2 = red[4] + red[5] + red[6] + red[7];
  const float mu = s * (1.f / CDIM);
  const float var = s2 * (1.f / CDIM) - mu * mu;
  const float rstd = rsqrtf(fmaxf(var, 0.f) + 1e-5f);
#pragma unroll
  for (int i = 0; i < 5; ++i) {
    const int c = threadIdx.x + 256 * i;
    H2[(size_t)row * CDIM + c] =
        (__bf16)((v[i] - mu) * rstd * (float)gamma[c] + (float)beta[c]);
  }
}

// ---------------- GEMM 64x128 tile, BK=64 (2 x 32 chunks), 2-barrier -------
// (R5 structure). nsplit>1: fp32 partials, no epilogue. Used for N=1280 GEMMs.
__global__ __launch_bounds__(256) void gemm64_kernel(
    const __bf16* __restrict__ A, const __bf16* __restrict__ Bt,
    const __bf16* __restrict__ bias, void* __restrict__ Cv,
    int M, int N, int K, int KS, int gelu, int nsplit) {
  __shared__ __bf16 As[2][64 * 32];
  __shared__ __bf16 Bs[2][128 * 32];
  const int bm = blockIdx.x, bn = blockIdx.y, sz = blockIdx.z;
  const int tid = threadIdx.x;
  const int lane = tid & 63, wave = tid >> 6;
  const int l16 = lane & 15, kq = (lane >> 4) << 3;
  const int lrow = lane >> 2, lcol = (lane & 3) << 3;
  const int wn = wave * 32;

  f32x4 acc[4][2];
  const f32x4 zero = {0.f, 0.f, 0.f, 0.f};
#pragma unroll
  for (int i = 0; i < 4; ++i)
#pragma unroll
    for (int j = 0; j < 2; ++j) acc[i][j] = zero;

  const int kbeg = sz * KS;
  int kend = kbeg + KS;
  if (kend > K) kend = K;

  int ga = bm * 64 + wave * 16 + lrow;
  if (ga > M - 1) ga = M - 1;  // clamp: garbage rows never stored
  const __bf16* Ap = A + (size_t)ga * K + lcol;

  for (int k0 = kbeg; k0 < kend; k0 += 64) {
#pragma unroll
    for (int c = 0; c < 2; ++c)
      GLOAD_LDS16(Ap + k0 + c * 32, &As[c][wave * 512]);
#pragma unroll
    for (int c = 0; c < 2; ++c)
#pragma unroll
      for (int t = 0; t < 2; ++t) {
        const int seg = t * 4 + wave;
        const int gb = bn * 128 + seg * 16 + lrow;  // N multiple of 128
        GLOAD_LDS16(Bt + (size_t)gb * K + k0 + c * 32 + lcol, &Bs[c][seg * 512]);
      }
    __syncthreads();
    bf16x8 af[4][2], bfr[2][2];
#pragma unroll
    for (int i = 0; i < 4; ++i)
#pragma unroll
      for (int c = 0; c < 2; ++c)
        af[i][c] = *(const bf16x8*)(&As[c][(i * 16 + l16) * 32 + kq]);
#pragma unroll
    for (int j = 0; j < 2; ++j)
#pragma unroll
      for (int c = 0; c < 2; ++c)
        bfr[j][c] = *(const bf16x8*)(&Bs[c][(wn + j * 16 + l16) * 32 + kq]);
#pragma unroll
    for (int i = 0; i < 4; ++i)
#pragma unroll
      for (int j = 0; j < 2; ++j)
#pragma unroll
        for (int c = 0; c < 2; ++c)
          acc[i][j] = __builtin_amdgcn_mfma_f32_16x16x32_bf16(af[i][c], bfr[j][c],
                                                              acc[i][j], 0, 0, 0);
    __syncthreads();
  }

  const int rq4 = (lane >> 4) * 4;
  if (nsplit > 1) {
    float* P = (float*)Cv + (size_t)sz * M * N;
#pragma unroll
    for (int i = 0; i < 4; ++i)
#pragma unroll
      for (int r = 0; r < 4; ++r) {
        const int grow = bm * 64 + i * 16 + rq4 + r;
        if (grow >= M) continue;
#pragma unroll
        for (int j = 0; j < 2; ++j) {
          const int gcol = bn * 128 + wn + j * 16 + l16;
          P[(size_t)grow * N + gcol] = acc[i][j][r];
        }
      }
  } else {
    __bf16* Cb = (__bf16*)Cv;
#pragma unroll
    for (int i = 0; i < 4; ++i)
#pragma unroll
      for (int r = 0; r < 4; ++r) {
        const int grow = bm * 64 + i * 16 + rq4 + r;
        if (grow >= M) continue;
#pragma unroll
        for (int j = 0; j < 2; ++j) {
          const int gcol = bn * 128 + wn + j * 16 + l16;
          float vv = acc[i][j][r];
          if (bias) vv += (float)bias[gcol];
          if (gelu) vv = 0.5f * vv * (1.f + erff(vv * 0.70710678118654752f));
          Cb[(size_t)grow * N + gcol] = (__bf16)vv;
        }
      }
  }
}

// ---------------- GEMM 256x256, BK=64, m201-template port ------------------
// 8 waves (2M x 4N), wave-tile 128x64, 4 phases/K-tile (mf-group x kc),
// per-phase: {2 gloads; counted vmcnt; barrier; 4-8 ds_reads; lgkmcnt(0);
// setprio(1); 16 MFMA; setprio(0); barrier}. Staging pairs per tile:
// (B0,B1)(B2,B3)(A0,A2)(A1,A3) -> B cover 3-4 phases, A cover 2 phases.
// Never drains vmcnt in steady state. N % 256 == 0.
__global__ __launch_bounds__(512, 2) void gemm256_kernel(
    const __bf16* __restrict__ A, const __bf16* __restrict__ Bt,
    const __bf16* __restrict__ bias, __bf16* __restrict__ C,
    int M, int N, int K, int gelu, int mtiles) {
  __shared__ __bf16 As[2][256 * 64];   // 64 KiB
  __shared__ __bf16 Bs[2][256 * 64];   // 64 KiB

  // bijective XCD swizzle (m204)
  const int nwg = mtiles * (N >> 8);
  const int qq = nwg >> 3, rr = nwg & 7;
  const int xcd = blockIdx.x & 7, rk = blockIdx.x >> 3;
  const int wg = (xcd < rr ? xcd * (qq + 1) : rr * (qq + 1) + (xcd - rr) * qq) + rk;
  const int bm = wg % mtiles, bn = wg / mtiles;

  const int tid = threadIdx.x;
  const int lane = tid & 63, wave = tid >> 6;
  const int wm = wave >> 2, wn = wave & 3;          // 2 x 4 wave grid
  const int l16 = lane & 15, quad = lane >> 4;

  // staging: set s = 64 rows x 64 k; 512 threads x 16 B cover one set.
  // linear LDS dest + inverse-swizzled global source (rule 21)
  const int rT = tid >> 3, sl = tid & 7;
  const int aoff = ((sl * 16) ^ ((rT & 7) << 4)) >> 1;   // elems
  const __bf16* Ap[4];
  const __bf16* Bp[4];
#pragma unroll
  for (int s = 0; s < 4; ++s) {
    int gm = bm * 256 + s * 64 + rT;
    if (gm > M - 1) gm = M - 1;      // clamp: garbage rows never stored
    Ap[s] = A + (size_t)gm * K + aoff;
    Bp[s] = Bt + (size_t)(bn * 256 + s * 64 + rT) * K + aoff;
  }
  const int ldst = tid * 8;          // dest elem offset within a set

  // swizzled ds_read k-offsets (elems); read-row & 7 == l16 & 7 always
  const int xsw = (l16 & 7) << 4;
  const int kb0 = ((quad << 4) ^ xsw) >> 1;
  const int kb1 = (((quad << 4) + 64) ^ xsw) >> 1;
  const int arow = (wm * 128 + l16) * 64;   // + mf*1024 (+4096 for mf4-7)
  const int brow = (wn * 64 + l16) * 64;    // + nf*1024

  f32x4 acc[8][4];
  const f32x4 zero = {0.f, 0.f, 0.f, 0.f};
#pragma unroll
  for (int i = 0; i < 8; ++i)
#pragma unroll
    for (int j = 0; j < 4; ++j) acc[i][j] = zero;

  const int NT = K >> 6;
  // prologue: tile0 pairs in deadline order (B0,B1)(B2,B3)(A0,A2)(A1,A3)
  GLOAD_LDS16(Bp[0], &Bs[0][0 * 4096 + ldst]);
  GLOAD_LDS16(Bp[1], &Bs[0][1 * 4096 + ldst]);
  GLOAD_LDS16(Bp[2], &Bs[0][2 * 4096 + ldst]);
  GLOAD_LDS16(Bp[3], &Bs[0][3 * 4096 + ldst]);
  GLOAD_LDS16(Ap[0], &As[0][0 * 4096 + ldst]);
  GLOAD_LDS16(Ap[2], &As[0][2 * 4096 + ldst]);
  GLOAD_LDS16(Ap[1], &As[0][1 * 4096 + ldst]);
  GLOAD_LDS16(Ap[3], &As[0][3 * 4096 + ldst]);

  bf16x8 af[4], ag[4], bfr[4];
  for (int t = 0; t < NT; ++t) {
    const int cur = t & 1;
    const int k1 = (t + 1) << 6;
    const bool pf = (t + 1 < NT);
    __bf16* Asn = &As[cur ^ 1][0];
    __bf16* Bsn = &Bs[cur ^ 1][0];
    const __bf16* Asc = &As[cur][0];
    const __bf16* Bsc = &Bs[cur][0];

    // -------- P0: (mf0-3 x nf0-3, kc0); stage next (B0,B1) --------
    if (pf) {
      GLOAD_LDS16(Bp[0] + k1, Bsn + 0 * 4096 + ldst);
      GLOAD_LDS16(Bp[1] + k1, Bsn + 1 * 4096 + ldst);
      asm volatile("s_waitcnt vmcnt(4)" ::: "memory");   // forces (A0,A2) of cur
    } else {
      asm volatile("s_waitcnt vmcnt(2)" ::: "memory");
    }
    __builtin_amdgcn_s_barrier();
#pragma unroll
    for (int i = 0; i < 4; ++i)
      af[i] = *(const bf16x8*)(Asc + arow + i * 1024 + kb0);
#pragma unroll
    for (int j = 0; j < 4; ++j)
      bfr[j] = *(const bf16x8*)(Bsc + brow + j * 1024 + kb0);
    asm volatile("s_waitcnt lgkmcnt(0)" ::: "memory");
    __builtin_amdgcn_sched_barrier(0);
    __builtin_amdgcn_s_setprio(1);
#pragma unroll
    for (int i = 0; i < 4; ++i)
#pragma unroll
      for (int j = 0; j < 4; ++j)
        acc[i][j] = __builtin_amdgcn_mfma_f32_16x16x32_bf16(af[i], bfr[j],
                                                            acc[i][j], 0, 0, 0);
    __builtin_amdgcn_s_setprio(0);
    __builtin_amdgcn_s_barrier();

    // -------- P1: (mf4-7 x nf0-3, kc0); stage next (B2,B3) --------
    if (pf) {
      GLOAD_LDS16(Bp[2] + k1, Bsn + 2 * 4096 + ldst);
      GLOAD_LDS16(Bp[3] + k1, Bsn + 3 * 4096 + ldst);
      asm volatile("s_waitcnt vmcnt(4)" ::: "memory");   // forces (A1,A3) of cur
    } else {
      asm volatile("s_waitcnt vmcnt(0)" ::: "memory");
    }
    __builtin_amdgcn_s_barrier();
#pragma unroll
    for (int i = 0; i < 4; ++i)
      ag[i] = *(const bf16x8*)(Asc + arow + 4096 + i * 1024 + kb0);
    asm volatile("s_waitcnt lgkmcnt(0)" ::: "memory");
    __builtin_amdgcn_sched_barrier(0);
    __builtin_amdgcn_s_setprio(1);
#pragma unroll
    for (int i = 0; i < 4; ++i)
#pragma unroll
      for (int j = 0; j < 4; ++j)
        acc[4 + i][j] = __builtin_amdgcn_mfma_f32_16x16x32_bf16(ag[i], bfr[j],
                                                                acc[4 + i][j], 0, 0, 0);
    __builtin_amdgcn_s_setprio(0);
    __builtin_amdgcn_s_barrier();

    // -------- P2: (mf0-3 x nf0-3, kc1); stage next (A0,A2) --------
    if (pf) {
      GLOAD_LDS16(Ap[0] + k1, Asn + 0 * 4096 + ldst);
      GLOAD_LDS16(Ap[2] + k1, Asn + 2 * 4096 + ldst);
    }
    __builtin_amdgcn_s_barrier();
#pragma unroll
    for (int i = 0; i < 4; ++i)
      af[i] = *(const bf16x8*)(Asc + arow + i * 1024 + kb1);
#pragma unroll
    for (int j = 0; j < 4; ++j)
      bfr[j] = *(const bf16x8*)(Bsc + brow + j * 1024 + kb1);
    asm volatile("s_waitcnt lgkmcnt(0)" ::: "memory");
    __builtin_amdgcn_sched_barrier(0);
    __builtin_amdgcn_s_setprio(1);
#pragma unroll
    for (int i = 0; i < 4; ++i)
#pragma unroll
      for (int j = 0; j < 4; ++j)
        acc[i][j] = __builtin_amdgcn_mfma_f32_16x16x32_bf16(af[i], bfr[j],
                                                            acc[i][j], 0, 0, 0);
    __builtin_amdgcn_s_setprio(0);
    __builtin_amdgcn_s_barrier();

    // -------- P3: (mf4-7 x nf0-3, kc1); stage next (A1,A3) --------
    if (pf) {
      GLOAD_LDS16(Ap[1] + k1, Asn + 1 * 4096 + ldst);
      GLOAD_LDS16(Ap[3] + k1, Asn + 3 * 4096 + ldst);
    }
    __builtin_amdgcn_s_barrier();
#pragma unroll
    for (int i = 0; i < 4; ++i)
      ag[i] = *(const bf16x8*)(Asc + arow + 4096 + i * 1024 + kb1);
    asm volatile("s_waitcnt lgkmcnt(0)" ::: "memory");
    __builtin_amdgcn_sched_barrier(0);
    __builtin_amdgcn_s_setprio(1);
#pragma unroll
    for (int i = 0; i < 4; ++i)
#pragma unroll
      for (int j = 0; j < 4; ++j)
        acc[4 + i][j] = __builtin_amdgcn_mfma_f32_16x16x32_bf16(ag[i], bfr[j],
                                                                acc[4 + i][j], 0, 0, 0);
    __builtin_amdgcn_s_setprio(0);
    __builtin_amdgcn_s_barrier();
  }

  // ----- epilogue -----
#pragma unroll
  for (int i = 0; i < 8; ++i)
#pragma unroll
    for (int r = 0; r < 4; ++r) {
      const int grow = bm * 256 + wm * 128 + i * 16 + quad * 4 + r;
      if (grow >= M) continue;
#pragma unroll
      for (int j = 0; j < 4; ++j) {
        const int gcol = bn * 256 + wn * 64 + j * 16 + l16;
        float vv = acc[i][j][r];
        if (bias) vv += (float)bias[gcol];
        if (gelu) vv = 0.5f * vv * (1.f + erff(vv * 0.70710678118654752f));
        C[(size_t)grow * N + gcol] = (__bf16)vv;
      }
    }
}

// ---------------- final reduce: out = resid + sum(P) + bias ----------------
__global__ __launch_bounds__(256) void reduce_kernel(
    const float* __restrict__ P, const __bf16* __restrict__ bias,
    const __bf16* __restrict__ resid, void* __restrict__ out,
    int MN, int N, const int* __restrict__ flag) {
  const int i = blockIdx.x * 256 + threadIdx.x;
  if (i >= MN) return;
  const float v = P[i] + P[(size_t)MN + i] + (float)bias[i % N] + (float)resid[i];
  if (flag[0]) ((__bf16*)out)[i] = (__bf16)v;
  else         ((float*)out)[i] = v;
}

// ---------------- MFMA flash attention, split-KV ---------------------------
__global__ __launch_bounds__(256) void attn_mfma_kernel(
    const __bf16* __restrict__ Q,    // fused base (+0), row stride rs
    const __bf16* __restrict__ Kk,   // fused base + 1280, row stride rs
    const __bf16* __restrict__ Vt,   // [CDIM][VTLD]
    float* __restrict__ Opart,       // [2][SEQ][CDIM]
    float* __restrict__ ml,          // [2][NHEAD][SEQ][2]
    int rs) {
  const int h = blockIdx.y;
  const int q0 = blockIdx.x * 64;
  const int z = blockIdx.z;
  const int tid = threadIdx.x;
  const int wave = tid >> 6, lane = tid & 63;
  const int l16 = lane & 15, quad = lane >> 4;

  __shared__ __bf16 Ks[64 * APAD];
  __shared__ __bf16 Vs[64 * APAD];
  __shared__ __bf16 Ps[4][16 * APAD];

  bf16x8 qf[2];
  {
    int q = q0 + wave * 16 + l16;
    if (q > SEQ - 1) q = SEQ - 1;
    const __bf16* qp = Q + (size_t)q * rs + h * DHEAD + quad * 8;
    qf[0] = *(const bf16x8*)(qp);
    qf[1] = *(const bf16x8*)(qp + 32);
  }

  f32x4 oacc[4];
  const f32x4 zero = {0.f, 0.f, 0.f, 0.f};
#pragma unroll
  for (int jt = 0; jt < 4; ++jt) oacc[jt] = zero;
  float mrow[4], lrow[4];
#pragma unroll
  for (int r = 0; r < 4; ++r) { mrow[r] = -30000.f; lrow[r] = 0.f; }

  const int srow = tid >> 2;
  const int scol = (tid & 3) << 4;

  const __bf16* Kbase = Kk + h * DHEAD;
  const __bf16* Vbase = Vt + (size_t)(h * DHEAD + srow) * VTLD;

  for (int kt = z * 12; kt < z * 12 + 12; ++kt) {
    const int key0 = kt * 64;
    __syncthreads();
    {
      int gk = key0 + srow;
      if (gk > SEQ - 1) gk = SEQ - 1;
      const __bf16* kp = Kbase + (size_t)gk * rs + scol;
      *(bf16x8*)(&Ks[srow * APAD + scol]) = *(const bf16x8*)(kp);
      *(bf16x8*)(&Ks[srow * APAD + scol + 8]) = *(const bf16x8*)(kp + 8);
      const __bf16* vp = Vbase + key0 + scol;
      *(bf16x8*)(&Vs[srow * APAD + scol]) = *(const bf16x8*)(vp);
      *(bf16x8*)(&Vs[srow * APAD + scol + 8]) = *(const bf16x8*)(vp + 8);
    }
    __syncthreads();

    f32x4 s[4];
#pragma unroll
    for (int jt = 0; jt < 4; ++jt) s[jt] = zero;
#pragma unroll
    for (int jt = 0; jt < 4; ++jt)
#pragma unroll
      for (int ks = 0; ks < 2; ++ks) {
        const bf16x8 kf = *(const bf16x8*)(&Ks[(jt * 16 + l16) * APAD + ks * 32 + quad * 8]);
        s[jt] = __builtin_amdgcn_mfma_f32_16x16x32_bf16(qf[ks], kf, s[jt], 0, 0, 0);
      }

#pragma unroll
    for (int jt = 0; jt < 4; ++jt) {
      const int key = key0 + jt * 16 + l16;
#pragma unroll
      for (int r = 0; r < 4; ++r) {
        float sv = s[jt][r] * 0.125f;
        if (key >= SEQ) sv = -30000.f;
        s[jt][r] = sv;
      }
    }

#pragma unroll
    for (int r = 0; r < 4; ++r) {
      float tmax = fmaxf(fmaxf(s[0][r], s[1][r]), fmaxf(s[2][r], s[3][r]));
#pragma unroll
      for (int off = 8; off > 0; off >>= 1) tmax = fmaxf(tmax, __shfl_xor(tmax, off));
      const float mnew = fmaxf(mrow[r], tmax);
      const float alpha = __expf(mrow[r] - mnew);
      mrow[r] = mnew;
      lrow[r] *= alpha;
#pragma unroll
      for (int jt = 0; jt < 4; ++jt) oacc[jt][r] *= alpha;
#pragma unroll
      for (int jt = 0; jt < 4; ++jt) {
        const float p = __expf(s[jt][r] - mnew);
        lrow[r] += p;
        Ps[wave][(quad * 4 + r) * APAD + jt * 16 + l16] = (__bf16)p;
      }
    }

    bf16x8 pf[2];
    pf[0] = *(const bf16x8*)(&Ps[wave][l16 * APAD + quad * 8]);
    pf[1] = *(const bf16x8*)(&Ps[wave][l16 * APAD + 32 + quad * 8]);
#pragma unroll
    for (int jt = 0; jt < 4; ++jt)
#pragma unroll
      for (int ks = 0; ks < 2; ++ks) {
        const bf16x8 vf = *(const bf16x8*)(&Vs[(jt * 16 + l16) * APAD + ks * 32 + quad * 8]);
        oacc[jt] = __builtin_amdgcn_mfma_f32_16x16x32_bf16(pf[ks], vf, oacc[jt], 0, 0, 0);
      }
  }

  float* Oz = Opart + (size_t)z * SEQ * CDIM;
#pragma unroll
  for (int r = 0; r < 4; ++r) {
    float lt = lrow[r];
#pragma unroll
    for (int off = 8; off > 0; off >>= 1) lt += __shfl_xor(lt, off);
    const int q = q0 + wave * 16 + quad * 4 + r;
    if (q < SEQ) {
#pragma unroll
      for (int jt = 0; jt < 4; ++jt)
        Oz[(size_t)q * CDIM + h * DHEAD + jt * 16 + l16] = oacc[jt][r];
      if (l16 == 0) {
        const size_t mi = ((size_t)(z * NHEAD + h) * SEQ + q) * 2;
        ml[mi] = mrow[r];
        ml[mi + 1] = lt;
      }
    }
  }
}

// ---------------- combine the two kv-halves --------------------------------
__global__ __launch_bounds__(256) void attn_combine_kernel(
    const float* __restrict__ Op, const float* __restrict__ ml,
    __bf16* __restrict__ O) {
  const int i = blockIdx.x * 256 + threadIdx.x;
  if (i >= SEQ * CDIM) return;
  const int q = i / CDIM;
  const int h = (i % CDIM) >> 6;
  const size_t m1i = ((size_t)h * SEQ + q) * 2;
  const size_t m2i = ((size_t)(NHEAD + h) * SEQ + q) * 2;
  const float m1 = ml[m1i], l1 = ml[m1i + 1];
  const float m2 = ml[m2i], l2 = ml[m2i + 1];
  const float M = fmaxf(m1, m2);
  const float e1 = __expf(m1 - M), e2 = __expf(m2 - M);
  const float v = (e1 * Op[i] + e2 * Op[(size_t)SEQ * CDIM + i]) /
                  (e1 * l1 + e2 * l2);
  O[i] = (__bf16)v;
}

// ---------------- launch ----------------
extern "C" void kernel_launch(void* const* d_in, const int* in_sizes, int n_in,
                              void* d_out, int out_size, void* d_ws, size_t ws_size,
                              hipStream_t stream) {
  const void* x   = d_in[0];
  const void* Wq  = d_in[1];
  const void* bq  = d_in[2];
  const void* Wk  = d_in[3];
  const void* Wv  = d_in[4];
  const void* bv  = d_in[5];
  const void* Wo  = d_in[6];
  const void* bo  = d_in[7];
  const void* g1  = d_in[8];
  const void* be1 = d_in[9];
  const void* g2  = d_in[10];
  const void* be2 = d_in[11];
  const void* W1  = d_in[12];
  const void* bm1 = d_in[13];
  const void* W2  = d_in[14];
  const void* bm2 = d_in[15];

  char* ws = (char*)d_ws;
  size_t off = 0;
  auto alloc = [&](size_t elems) {
    __bf16* p = (__bf16*)(ws + off);
    off += elems * sizeof(__bf16);
    return p;
  };
  __bf16* Wqkvt = alloc((size_t)QKVN * CDIM);   // Wq^T|Wk^T|Wv^T
  __bf16* Wot   = alloc((size_t)CDIM * CDIM);
  __bf16* W1t   = alloc((size_t)CDIM * NMLP);
  __bf16* W2t   = alloc((size_t)CDIM * NMLP);
  __bf16* qkvb  = alloc((size_t)SEQ * QKVN);    // fused q|k|v; later x1|h2
  __bf16* hb    = alloc((size_t)SEQ * CDIM);    // ln1 out / attn out
  __bf16* mb    = alloc((size_t)SEQ * NMLP);    // mlp hidden; head = Vt
  __bf16* pb    = alloc(20480);                 // packed params
  off = (off + 15) & ~(size_t)15;
  float* pscr = (float*)(ws + off);             // O-partials / split-K partials
  off += (size_t)2 * SEQ * CDIM * sizeof(float);
  float* mlb = (float*)(ws + off);              // attn (m,l): 2 x 20 x 1500 x 2
  off += (size_t)2 * NHEAD * SEQ * 2 * sizeof(float);
  int* flag = (int*)(ws + off);

  __bf16* vtb  = mb;                         // Vt[CDIM][VTLD] (dead before MLP1)
  __bf16* x1b  = qkvb;                       // x1 (qkv dead after attention)
  __bf16* h2b  = qkvb + (size_t)SEQ * CDIM;  // ln2 out

  __bf16* qkvbias = pb + 0;
  __bf16* bo_b  = pb + 3840;
  __bf16* g1_b  = pb + 5120;
  __bf16* be1_b = pb + 6400;
  __bf16* g2_b  = pb + 7680;
  __bf16* be2_b = pb + 8960;
  __bf16* b1_b  = pb + 10240;
  __bf16* b2_b  = pb + 15360;

  // 1. pack params (self-detect dtype; writes flag)
  pack_params_kernel<<<65, 256, 0, stream>>>(
      (const unsigned int*)x, bq, bv, bo, g1, be1, g2, be2, bm1, bm2, pb, flag);
  // 2. all weight transposes in one launch
  transpose_all_kernel<<<19200, dim3(32, 8), 0, stream>>>(
      Wq, Wk, Wv, Wo, W1, W2, Wqkvt, Wot, W1t, W2t, flag);
  // 3. h = LN1(x)
  ln_kernel<<<SEQ, 256, 0, stream>>>(x, g1_b, be1_b, hb, flag);
  // 4. qkv = h @ Wqkv^T + (bq|0|bv)   [1500][3840], 256^2 template, 90 blocks
  gemm256_kernel<<<90, 512, 0, stream>>>(
      hb, Wqkvt, qkvbias, qkvb, SEQ, QKVN, CDIM, 0, 6);
  // 5. Vt = V^T
  transpose_act_kernel<<<dim3(40, 47), dim3(32, 8), 0, stream>>>(
      qkvb + 2560, vtb, QKVN);
  // 6. attention split-KV partials
  attn_mfma_kernel<<<dim3(24, NHEAD, 2), 256, 0, stream>>>(
      qkvb, qkvb + 1280, vtb, pscr, mlb, QKVN);
  // 7. combine -> hb
  attn_combine_kernel<<<7500, 256, 0, stream>>>(pscr, mlb, hb);
  // 8. attn @ Wo (split-K=2, fp32 partials), 480 blocks
  gemm64_kernel<<<dim3(24, 10, 2), 256, 0, stream>>>(
      hb, Wot, nullptr, pscr, SEQ, CDIM, CDIM, 640, 0, 2);
  // 9. fused: x1 = x + partials + bo ; h2 = LN2(x1)
  resid_ln_kernel<<<SEQ, 256, 0, stream>>>(pscr, bo_b, x, g2_b, be2_b,
                                           x1b, h2b, flag);
  // 10. m = gelu(h2 @ W1 + b1)  (256^2 template, 120 blocks)
  gemm256_kernel<<<120, 512, 0, stream>>>(
      h2b, W1t, b1_b, mb, SEQ, NMLP, CDIM, 1, 6);
  // 11. m @ W2 (split-K=2), 480 blocks
  gemm64_kernel<<<dim3(24, 10, 2), 256, 0, stream>>>(
      mb, W2t, nullptr, pscr, SEQ, CDIM, NMLP, 2560, 0, 2);
  // 12. out = x1 + partials + b2 (output dtype per flag)
  reduce_kernel<<<7500, 256, 0, stream>>>(pscr, b2_b, x1b, d_out,
                                          SEQ * CDIM, CDIM, flag);
}

// Round 4
// 405.418 us; speedup vs baseline: 1.1347x; 1.1347x over previous
//
#include <hip/hip_runtime.h>
#include <hip/hip_bf16.h>
#include <math.h>

typedef __bf16 bf16x8 __attribute__((ext_vector_type(8)));
typedef float f32x4 __attribute__((ext_vector_type(4)));

#define SEQ 1500
#define CDIM 1280
#define NHEAD 20
#define DHEAD 64
#define NMLP 5120
#define QKVN 3840
#define VTLD 1504   // leading dim of transposed V (47*32)
#define APAD 68     // attention LDS stride

#define GLOAD_LDS16(gp, lp)                                                    \
  __builtin_amdgcn_global_load_lds(                                            \
      (const __attribute__((address_space(1))) unsigned int*)(gp),             \
      (__attribute__((address_space(3))) unsigned int*)(lp), 16, 0, 0)

// ---------------- pack params; each block self-detects dtype ----------------
// layout: [0,3840) qkvbias (bq|0|bv) | 3840 bo | 5120 g1 | 6400 be1 |
//         7680 g2 | 8960 be2 | 10240 b1(5120) | 15360 b2
__global__ __launch_bounds__(256) void pack_params_kernel(
    const unsigned int* __restrict__ xw, const void* bq, const void* bv,
    const void* bo, const void* g1, const void* be1, const void* g2,
    const void* be2, const void* b1, const void* b2,
    __bf16* __restrict__ pb, int* __restrict__ flag) {
  __shared__ int cnt[256];
  const unsigned int w = xw[threadIdx.x];
  const unsigned int e = (w >> 7) & 0xFF;
  cnt[threadIdx.x] = (e >= 100 && e <= 150) ? 1 : 0;
  __syncthreads();
  for (int s = 128; s > 0; s >>= 1) {
    if (threadIdx.x < (unsigned)s) cnt[threadIdx.x] += cnt[threadIdx.x + s];
    __syncthreads();
  }
  const int isbf = (cnt[0] >= 160) ? 1 : 0;
  if (blockIdx.x == 0 && threadIdx.x == 0) flag[0] = isbf;
  const int i = blockIdx.x * 256 + threadIdx.x;
  if (i >= 16640) return;
  auto ld = [&](const void* p, int j) -> float {
    return isbf ? (float)((const __bf16*)p)[j] : ((const float*)p)[j];
  };
  float v;
  if (i < 3840) {
    if (i < 1280) v = ld(bq, i);
    else if (i < 2560) v = 0.f;
    else v = ld(bv, i - 2560);
  } else if (i < 5120) v = ld(bo, i - 3840);
  else if (i < 6400) v = ld(g1, i - 5120);
  else if (i < 7680) v = ld(be1, i - 6400);
  else if (i < 8960) v = ld(g2, i - 7680);
  else if (i < 10240) v = ld(be2, i - 8960);
  else if (i < 15360) v = ld(b1, i - 10240);
  else v = ld(b2, i - 15360);
  pb[i] = (__bf16)v;
}

// ---------------- fused weight transpose: all 6 weights, one launch --------
__device__ __forceinline__ void transpose_body(const void* in, __bf16* out,
                                               int K, int N, int isbf,
                                               int bx, int by) {
  __shared__ __bf16 t[32][33];
  const int tx = threadIdx.x, ty = threadIdx.y;
  const int n0 = bx * 32, k0 = by * 32;
  if (isbf) {
    const __bf16* s = (const __bf16*)in;
#pragma unroll
    for (int i = ty; i < 32; i += 8)
      t[i][tx] = s[(size_t)(k0 + i) * N + n0 + tx];
  } else {
    const float* s = (const float*)in;
#pragma unroll
    for (int i = ty; i < 32; i += 8)
      t[i][tx] = (__bf16)s[(size_t)(k0 + i) * N + n0 + tx];
  }
  __syncthreads();
#pragma unroll
  for (int i = ty; i < 32; i += 8)
    out[(size_t)(n0 + i) * K + k0 + tx] = t[tx][i];
}

__global__ __launch_bounds__(256) void transpose_all_kernel(
    const void* Wq, const void* Wk, const void* Wv, const void* Wo,
    const void* W1, const void* W2, __bf16* __restrict__ Wqkvt,
    __bf16* __restrict__ Wot, __bf16* __restrict__ W1t,
    __bf16* __restrict__ W2t, const int* __restrict__ flag) {
  const int id = blockIdx.x;
  const int isbf = flag[0];
  if (id < 6400) {                      // Wq|Wk|Wv|Wo : 4 x (40x40)
    const int w = id / 1600, r = id % 1600;
    const void* in = (w == 0) ? Wq : (w == 1) ? Wk : (w == 2) ? Wv : Wo;
    __bf16* out = (w < 3) ? (Wqkvt + (size_t)w * CDIM * CDIM) : Wot;
    transpose_body(in, out, CDIM, CDIM, isbf, r % 40, r / 40);
  } else if (id < 12800) {              // W1 : 160x40
    const int r = id - 6400;
    transpose_body(W1, W1t, CDIM, NMLP, isbf, r % 160, r / 160);
  } else {                              // W2 : 40x160
    const int r = id - 12800;
    transpose_body(W2, W2t, NMLP, CDIM, isbf, r % 40, r / 40);
  }
}

// ---------------- activation transpose: [SEQ][.] -> [N][VTLD] --------------
__global__ __launch_bounds__(256) void transpose_act_kernel(const __bf16* __restrict__ in,
                                                            __bf16* __restrict__ out,
                                                            int istride) {
  __shared__ __bf16 t[32][33];
  const int tx = threadIdx.x, ty = threadIdx.y;
  const int n0 = blockIdx.x * 32, k0 = blockIdx.y * 32;
#pragma unroll
  for (int i = ty; i < 32; i += 8) {
    const int k = k0 + i;
    t[i][tx] = (k < SEQ) ? in[(size_t)k * istride + n0 + tx] : (__bf16)0.f;
  }
  __syncthreads();
#pragma unroll
  for (int i = ty; i < 32; i += 8) {
    const int kk = k0 + tx;
    if (kk < VTLD) out[(size_t)(n0 + i) * VTLD + kk] = t[tx][i];
  }
}

// ---------------- layernorm 1 (row-major out); X dtype per flag ------------
__global__ __launch_bounds__(256) void ln_kernel(const void* __restrict__ X,
                                                 const __bf16* __restrict__ gamma,
                                                 const __bf16* __restrict__ beta,
                                                 __bf16* __restrict__ Y,
                                                 const int* __restrict__ flag) {
  const int isf32 = (flag[0] == 0);
  const int row = blockIdx.x;
  float v[5];
  float s = 0.f, s2 = 0.f;
#pragma unroll
  for (int i = 0; i < 5; ++i) {
    const int c = threadIdx.x + 256 * i;
    const size_t idx = (size_t)row * CDIM + c;
    v[i] = isf32 ? ((const float*)X)[idx] : (float)((const __bf16*)X)[idx];
    s += v[i];
    s2 += v[i] * v[i];
  }
  const int lane = threadIdx.x & 63, wv = threadIdx.x >> 6;
#pragma unroll
  for (int off = 32; off > 0; off >>= 1) {
    s += __shfl_down(s, off);
    s2 += __shfl_down(s2, off);
  }
  __shared__ float red[8];
  if (lane == 0) { red[wv] = s; red[4 + wv] = s2; }
  __syncthreads();
  s = red[0] + red[1] + red[2] + red[3];
  s2 = red[4] + red[5] + red[6] + red[7];
  const float mu = s * (1.f / CDIM);
  const float var = s2 * (1.f / CDIM) - mu * mu;
  const float rstd = rsqrtf(fmaxf(var, 0.f) + 1e-5f);
#pragma unroll
  for (int i = 0; i < 5; ++i) {
    const int c = threadIdx.x + 256 * i;
    Y[(size_t)row * CDIM + c] =
        (__bf16)((v[i] - mu) * rstd * (float)gamma[c] + (float)beta[c]);
  }
}

// ---------------- fused: x1 = x + sum(P) + bo ; h2 = LN2(x1) ----------------
__global__ __launch_bounds__(256) void resid_ln_kernel(
    const float* __restrict__ P, const __bf16* __restrict__ bo,
    const void* __restrict__ X, const __bf16* __restrict__ gamma,
    const __bf16* __restrict__ beta, __bf16* __restrict__ X1,
    __bf16* __restrict__ H2, const int* __restrict__ flag) {
  const int isf32 = (flag[0] == 0);
  const int row = blockIdx.x;
  const int MN = SEQ * CDIM;
  float v[5];
  float s = 0.f, s2 = 0.f;
#pragma unroll
  for (int i = 0; i < 5; ++i) {
    const int c = threadIdx.x + 256 * i;
    const size_t idx = (size_t)row * CDIM + c;
    const float xv = isf32 ? ((const float*)X)[idx] : (float)((const __bf16*)X)[idx];
    const float val = P[idx] + P[MN + idx] + (float)bo[c] + xv;
    X1[idx] = (__bf16)val;
    v[i] = val;
    s += val;
    s2 += val * val;
  }
  const int lane = threadIdx.x & 63, wv = threadIdx.x >> 6;
#pragma unroll
  for (int off = 32; off > 0; off >>= 1) {
    s += __shfl_down(s, off);
    s2 += __shfl_down(s2, off);
  }
  __shared__ float red[8];
  if (lane == 0) { red[wv] = s; red[4 + wv] = s2; }
  __syncthreads();
  s = red[0] + red[1] + red[2] + red[3];
  s2 = red[4] + red[5] + red[6] + red[7];
  const float mu = s * (1.f / CDIM);
  const float var = s2 * (1.f / CDIM) - mu * mu;
  const float rstd = rsqrtf(fmaxf(var, 0.f) + 1e-5f);
#pragma unroll
  for (int i = 0; i < 5; ++i) {
    const int c = threadIdx.x + 256 * i;
    H2[(size_t)row * CDIM + c] =
        (__bf16)((v[i] - mu) * rstd * (float)gamma[c] + (float)beta[c]);
  }
}

// ---------------- GEMM 64x128 tile, BK=64 (2 x 32 chunks), 2-barrier -------
// (R5 structure). nsplit>1: fp32 partials, no epilogue. Used for N=1280 GEMMs.
__global__ __launch_bounds__(256) void gemm64_kernel(
    const __bf16* __restrict__ A, const __bf16* __restrict__ Bt,
    const __bf16* __restrict__ bias, void* __restrict__ Cv,
    int M, int N, int K, int KS, int gelu, int nsplit) {
  __shared__ __bf16 As[2][64 * 32];
  __shared__ __bf16 Bs[2][128 * 32];
  const int bm = blockIdx.x, bn = blockIdx.y, sz = blockIdx.z;
  const int tid = threadIdx.x;
  const int lane = tid & 63, wave = tid >> 6;
  const int l16 = lane & 15, kq = (lane >> 4) << 3;
  const int lrow = lane >> 2, lcol = (lane & 3) << 3;
  const int wn = wave * 32;

  f32x4 acc[4][2];
  const f32x4 zero = {0.f, 0.f, 0.f, 0.f};
#pragma unroll
  for (int i = 0; i < 4; ++i)
#pragma unroll
    for (int j = 0; j < 2; ++j) acc[i][j] = zero;

  const int kbeg = sz * KS;
  int kend = kbeg + KS;
  if (kend > K) kend = K;

  int ga = bm * 64 + wave * 16 + lrow;
  if (ga > M - 1) ga = M - 1;  // clamp: garbage rows never stored
  const __bf16* Ap = A + (size_t)ga * K + lcol;

  for (int k0 = kbeg; k0 < kend; k0 += 64) {
#pragma unroll
    for (int c = 0; c < 2; ++c)
      GLOAD_LDS16(Ap + k0 + c * 32, &As[c][wave * 512]);
#pragma unroll
    for (int c = 0; c < 2; ++c)
#pragma unroll
      for (int t = 0; t < 2; ++t) {
        const int seg = t * 4 + wave;
        const int gb = bn * 128 + seg * 16 + lrow;  // N multiple of 128
        GLOAD_LDS16(Bt + (size_t)gb * K + k0 + c * 32 + lcol, &Bs[c][seg * 512]);
      }
    __syncthreads();
    bf16x8 af[4][2], bfr[2][2];
#pragma unroll
    for (int i = 0; i < 4; ++i)
#pragma unroll
      for (int c = 0; c < 2; ++c)
        af[i][c] = *(const bf16x8*)(&As[c][(i * 16 + l16) * 32 + kq]);
#pragma unroll
    for (int j = 0; j < 2; ++j)
#pragma unroll
      for (int c = 0; c < 2; ++c)
        bfr[j][c] = *(const bf16x8*)(&Bs[c][(wn + j * 16 + l16) * 32 + kq]);
#pragma unroll
    for (int i = 0; i < 4; ++i)
#pragma unroll
      for (int j = 0; j < 2; ++j)
#pragma unroll
        for (int c = 0; c < 2; ++c)
          acc[i][j] = __builtin_amdgcn_mfma_f32_16x16x32_bf16(af[i][c], bfr[j][c],
                                                              acc[i][j], 0, 0, 0);
    __syncthreads();
  }

  const int rq4 = (lane >> 4) * 4;
  if (nsplit > 1) {
    float* P = (float*)Cv + (size_t)sz * M * N;
#pragma unroll
    for (int i = 0; i < 4; ++i)
#pragma unroll
      for (int r = 0; r < 4; ++r) {
        const int grow = bm * 64 + i * 16 + rq4 + r;
        if (grow >= M) continue;
#pragma unroll
        for (int j = 0; j < 2; ++j) {
          const int gcol = bn * 128 + wn + j * 16 + l16;
          P[(size_t)grow * N + gcol] = acc[i][j][r];
        }
      }
  } else {
    __bf16* Cb = (__bf16*)Cv;
#pragma unroll
    for (int i = 0; i < 4; ++i)
#pragma unroll
      for (int r = 0; r < 4; ++r) {
        const int grow = bm * 64 + i * 16 + rq4 + r;
        if (grow >= M) continue;
#pragma unroll
        for (int j = 0; j < 2; ++j) {
          const int gcol = bn * 128 + wn + j * 16 + l16;
          float vv = acc[i][j][r];
          if (bias) vv += (float)bias[gcol];
          if (gelu) vv = 0.5f * vv * (1.f + erff(vv * 0.70710678118654752f));
          Cb[(size_t)grow * N + gcol] = (__bf16)vv;
        }
      }
  }
}

// ---------------- GEMM 64x256, B streamed global->reg (AITER pattern) ------
// A through LDS (dbuf, XOR-swizzled, gload_lds w16); B-fragments loaded
// directly from L2-resident Bt[N][K] into MFMA registers, double-buffered
// one K-tile ahead (named bA/bB, rule #20). LDS traffic halved -> MFMA-bound.
// 4 waves (1x4 over N), wave-tile 64x64, BK=64. Requires K%128==0, N%256==0.
__global__ __launch_bounds__(256, 2) void gemmbg_kernel(
    const __bf16* __restrict__ A, const __bf16* __restrict__ Bt,
    const __bf16* __restrict__ bias, __bf16* __restrict__ C,
    int M, int N, int K, int gelu, int mtiles) {
  __shared__ __bf16 As[2][64 * 64];   // 16 KiB dbuf

  // bijective chunked XCD swizzle (m204); bm fastest -> same-XCD blocks share bn
  const int nwg = mtiles * (N >> 8);
  const int qq = nwg >> 3, rr = nwg & 7;
  const int xcd = blockIdx.x & 7, rk = blockIdx.x >> 3;
  const int wg = (xcd < rr ? xcd * (qq + 1) : rr * (qq + 1) + (xcd - rr) * qq) + rk;
  const int bm = wg % mtiles, bn = wg / mtiles;

  const int tid = threadIdx.x;
  const int lane = tid & 63, wave = tid >> 6;
  const int l16 = lane & 15, quad = lane >> 4;

  // ---- A staging: linear LDS dest + inverse-swizzled global source (rule 21)
  const int rA = tid >> 3, sl = tid & 7;            // row 0..31, 16B slot 0..7
  const int aswz = ((sl * 16) ^ ((rA & 7) << 4)) >> 1;   // elems
  int gm0 = bm * 64 + rA;      if (gm0 > M - 1) gm0 = M - 1;
  int gm1 = bm * 64 + 32 + rA; if (gm1 > M - 1) gm1 = M - 1;
  const __bf16* Ap0 = A + (size_t)gm0 * K + aswz;
  const __bf16* Ap1 = A + (size_t)gm1 * K + aswz;

  // ---- B pointers: one row per (j,l16); quad covers 4x16B of 64 contig bytes
  const __bf16* Bp[4];
#pragma unroll
  for (int j = 0; j < 4; ++j)
    Bp[j] = Bt + (size_t)(bn * 256 + wave * 64 + j * 16 + l16) * K + quad * 8;

  // ---- swizzled A ds_read byte offsets within a 128B row
  const int xsw = (l16 & 7) << 4;
  const int kb0 = ((quad * 16) ^ xsw) >> 1;          // kc=0, elems
  const int kb1 = ((64 + quad * 16) ^ xsw) >> 1;     // kc=1, elems

  f32x4 acc[4][4];
  const f32x4 zero = {0.f, 0.f, 0.f, 0.f};
#pragma unroll
  for (int i = 0; i < 4; ++i)
#pragma unroll
    for (int j = 0; j < 4; ++j) acc[i][j] = zero;

  const int NT = K >> 6;   // 20 for K=1280 (even; loop is 2x unrolled)

#define STAGE_A(b, k0)                                  \
  do {                                                  \
    GLOAD_LDS16(Ap0 + (k0), &As[b][tid * 8]);           \
    GLOAD_LDS16(Ap1 + (k0), &As[b][2048 + tid * 8]);    \
  } while (0)

#define LOAD_B(bf, k0)                                  \
  do {                                                  \
    _Pragma("unroll")                                   \
    for (int j = 0; j < 4; ++j) {                       \
      bf[j][0] = *(const bf16x8*)(Bp[j] + (k0));        \
      bf[j][1] = *(const bf16x8*)(Bp[j] + (k0) + 32);   \
    }                                                   \
  } while (0)

#define COMPUTE(b, bf)                                                        \
  do {                                                                        \
    bf16x8 af[4][2];                                                          \
    _Pragma("unroll")                                                         \
    for (int i = 0; i < 4; ++i) {                                             \
      const int rb = (i * 16 + l16) * 64;                                     \
      af[i][0] = *(const bf16x8*)(&As[b][rb + kb0]);                          \
      af[i][1] = *(const bf16x8*)(&As[b][rb + kb1]);                          \
    }                                                                         \
    _Pragma("unroll")                                                         \
    for (int i = 0; i < 4; ++i)                                               \
      _Pragma("unroll")                                                       \
      for (int j = 0; j < 4; ++j) {                                           \
        acc[i][j] = __builtin_amdgcn_mfma_f32_16x16x32_bf16(af[i][0], bf[j][0],\
                                                            acc[i][j], 0, 0, 0);\
        acc[i][j] = __builtin_amdgcn_mfma_f32_16x16x32_bf16(af[i][1], bf[j][1],\
                                                            acc[i][j], 0, 0, 0);\
      }                                                                       \
  } while (0)

  bf16x8 bA[4][2], bB[4][2];
  STAGE_A(0, 0);
  LOAD_B(bA, 0);
  for (int t = 0; t < NT; t += 2) {
    __syncthreads();                       // As[0] + bA ready (cover = prev half)
    if (t + 1 < NT) { STAGE_A(1, (t + 1) * 64); LOAD_B(bB, (t + 1) * 64); }
    COMPUTE(0, bA);
    __syncthreads();                       // As[1] + bB ready (cover = COMPUTE)
    if (t + 2 < NT) { STAGE_A(0, (t + 2) * 64); LOAD_B(bA, (t + 2) * 64); }
    COMPUTE(1, bB);
  }
#undef STAGE_A
#undef LOAD_B
#undef COMPUTE

  // ----- epilogue -----
#pragma unroll
  for (int i = 0; i < 4; ++i)
#pragma unroll
    for (int r = 0; r < 4; ++r) {
      const int grow = bm * 64 + i * 16 + quad * 4 + r;
      if (grow >= M) continue;
#pragma unroll
      for (int j = 0; j < 4; ++j) {
        const int gcol = bn * 256 + wave * 64 + j * 16 + l16;
        float vv = acc[i][j][r];
        if (bias) vv += (float)bias[gcol];
        if (gelu) vv = 0.5f * vv * (1.f + erff(vv * 0.70710678118654752f));
        C[(size_t)grow * N + gcol] = (__bf16)vv;
      }
    }
}

// ---------------- final reduce: out = resid + sum(P) + bias ----------------
__global__ __launch_bounds__(256) void reduce_kernel(
    const float* __restrict__ P, const __bf16* __restrict__ bias,
    const __bf16* __restrict__ resid, void* __restrict__ out,
    int MN, int N, const int* __restrict__ flag) {
  const int i = blockIdx.x * 256 + threadIdx.x;
  if (i >= MN) return;
  const float v = P[i] + P[(size_t)MN + i] + (float)bias[i % N] + (float)resid[i];
  if (flag[0]) ((__bf16*)out)[i] = (__bf16)v;
  else         ((float*)out)[i] = v;
}

// ---------------- MFMA flash attention, split-KV ---------------------------
__global__ __launch_bounds__(256) void attn_mfma_kernel(
    const __bf16* __restrict__ Q,    // fused base (+0), row stride rs
    const __bf16* __restrict__ Kk,   // fused base + 1280, row stride rs
    const __bf16* __restrict__ Vt,   // [CDIM][VTLD]
    float* __restrict__ Opart,       // [2][SEQ][CDIM]
    float* __restrict__ ml,          // [2][NHEAD][SEQ][2]
    int rs) {
  const int h = blockIdx.y;
  const int q0 = blockIdx.x * 64;
  const int z = blockIdx.z;
  const int tid = threadIdx.x;
  const int wave = tid >> 6, lane = tid & 63;
  const int l16 = lane & 15, quad = lane >> 4;

  __shared__ __bf16 Ks[64 * APAD];
  __shared__ __bf16 Vs[64 * APAD];
  __shared__ __bf16 Ps[4][16 * APAD];

  bf16x8 qf[2];
  {
    int q = q0 + wave * 16 + l16;
    if (q > SEQ - 1) q = SEQ - 1;
    const __bf16* qp = Q + (size_t)q * rs + h * DHEAD + quad * 8;
    qf[0] = *(const bf16x8*)(qp);
    qf[1] = *(const bf16x8*)(qp + 32);
  }

  f32x4 oacc[4];
  const f32x4 zero = {0.f, 0.f, 0.f, 0.f};
#pragma unroll
  for (int jt = 0; jt < 4; ++jt) oacc[jt] = zero;
  float mrow[4], lrow[4];
#pragma unroll
  for (int r = 0; r < 4; ++r) { mrow[r] = -30000.f; lrow[r] = 0.f; }

  const int srow = tid >> 2;
  const int scol = (tid & 3) << 4;

  const __bf16* Kbase = Kk + h * DHEAD;
  const __bf16* Vbase = Vt + (size_t)(h * DHEAD + srow) * VTLD;

  for (int kt = z * 12; kt < z * 12 + 12; ++kt) {
    const int key0 = kt * 64;
    __syncthreads();
    {
      int gk = key0 + srow;
      if (gk > SEQ - 1) gk = SEQ - 1;
      const __bf16* kp = Kbase + (size_t)gk * rs + scol;
      *(bf16x8*)(&Ks[srow * APAD + scol]) = *(const bf16x8*)(kp);
      *(bf16x8*)(&Ks[srow * APAD + scol + 8]) = *(const bf16x8*)(kp + 8);
      const __bf16* vp = Vbase + key0 + scol;
      *(bf16x8*)(&Vs[srow * APAD + scol]) = *(const bf16x8*)(vp);
      *(bf16x8*)(&Vs[srow * APAD + scol + 8]) = *(const bf16x8*)(vp + 8);
    }
    __syncthreads();

    f32x4 s[4];
#pragma unroll
    for (int jt = 0; jt < 4; ++jt) s[jt] = zero;
#pragma unroll
    for (int jt = 0; jt < 4; ++jt)
#pragma unroll
      for (int ks = 0; ks < 2; ++ks) {
        const bf16x8 kf = *(const bf16x8*)(&Ks[(jt * 16 + l16) * APAD + ks * 32 + quad * 8]);
        s[jt] = __builtin_amdgcn_mfma_f32_16x16x32_bf16(qf[ks], kf, s[jt], 0, 0, 0);
      }

#pragma unroll
    for (int jt = 0; jt < 4; ++jt) {
      const int key = key0 + jt * 16 + l16;
#pragma unroll
      for (int r = 0; r < 4; ++r) {
        float sv = s[jt][r] * 0.125f;
        if (key >= SEQ) sv = -30000.f;
        s[jt][r] = sv;
      }
    }

#pragma unroll
    for (int r = 0; r < 4; ++r) {
      float tmax = fmaxf(fmaxf(s[0][r], s[1][r]), fmaxf(s[2][r], s[3][r]));
#pragma unroll
      for (int off = 8; off > 0; off >>= 1) tmax = fmaxf(tmax, __shfl_xor(tmax, off));
      const float mnew = fmaxf(mrow[r], tmax);
      const float alpha = __expf(mrow[r] - mnew);
      mrow[r] = mnew;
      lrow[r] *= alpha;
#pragma unroll
      for (int jt = 0; jt < 4; ++jt) oacc[jt][r] *= alpha;
#pragma unroll
      for (int jt = 0; jt < 4; ++jt) {
        const float p = __expf(s[jt][r] - mnew);
        lrow[r] += p;
        Ps[wave][(quad * 4 + r) * APAD + jt * 16 + l16] = (__bf16)p;
      }
    }

    bf16x8 pf[2];
    pf[0] = *(const bf16x8*)(&Ps[wave][l16 * APAD + quad * 8]);
    pf[1] = *(const bf16x8*)(&Ps[wave][l16 * APAD + 32 + quad * 8]);
#pragma unroll
    for (int jt = 0; jt < 4; ++jt)
#pragma unroll
      for (int ks = 0; ks < 2; ++ks) {
        const bf16x8 vf = *(const bf16x8*)(&Vs[(jt * 16 + l16) * APAD + ks * 32 + quad * 8]);
        oacc[jt] = __builtin_amdgcn_mfma_f32_16x16x32_bf16(pf[ks], vf, oacc[jt], 0, 0, 0);
      }
  }

  float* Oz = Opart + (size_t)z * SEQ * CDIM;
#pragma unroll
  for (int r = 0; r < 4; ++r) {
    float lt = lrow[r];
#pragma unroll
    for (int off = 8; off > 0; off >>= 1) lt += __shfl_xor(lt, off);
    const int q = q0 + wave * 16 + quad * 4 + r;
    if (q < SEQ) {
#pragma unroll
      for (int jt = 0; jt < 4; ++jt)
        Oz[(size_t)q * CDIM + h * DHEAD + jt * 16 + l16] = oacc[jt][r];
      if (l16 == 0) {
        const size_t mi = ((size_t)(z * NHEAD + h) * SEQ + q) * 2;
        ml[mi] = mrow[r];
        ml[mi + 1] = lt;
      }
    }
  }
}

// ---------------- combine the two kv-halves --------------------------------
__global__ __launch_bounds__(256) void attn_combine_kernel(
    const float* __restrict__ Op, const float* __restrict__ ml,
    __bf16* __restrict__ O) {
  const int i = blockIdx.x * 256 + threadIdx.x;
  if (i >= SEQ * CDIM) return;
  const int q = i / CDIM;
  const int h = (i % CDIM) >> 6;
  const size_t m1i = ((size_t)h * SEQ + q) * 2;
  const size_t m2i = ((size_t)(NHEAD + h) * SEQ + q) * 2;
  const float m1 = ml[m1i], l1 = ml[m1i + 1];
  const float m2 = ml[m2i], l2 = ml[m2i + 1];
  const float M = fmaxf(m1, m2);
  const float e1 = __expf(m1 - M), e2 = __expf(m2 - M);
  const float v = (e1 * Op[i] + e2 * Op[(size_t)SEQ * CDIM + i]) /
                  (e1 * l1 + e2 * l2);
  O[i] = (__bf16)v;
}

// ---------------- launch ----------------
extern "C" void kernel_launch(void* const* d_in, const int* in_sizes, int n_in,
                              void* d_out, int out_size, void* d_ws, size_t ws_size,
                              hipStream_t stream) {
  const void* x   = d_in[0];
  const void* Wq  = d_in[1];
  const void* bq  = d_in[2];
  const void* Wk  = d_in[3];
  const void* Wv  = d_in[4];
  const void* bv  = d_in[5];
  const void* Wo  = d_in[6];
  const void* bo  = d_in[7];
  const void* g1  = d_in[8];
  const void* be1 = d_in[9];
  const void* g2  = d_in[10];
  const void* be2 = d_in[11];
  const void* W1  = d_in[12];
  const void* bm1 = d_in[13];
  const void* W2  = d_in[14];
  const void* bm2 = d_in[15];

  char* ws = (char*)d_ws;
  size_t off = 0;
  auto alloc = [&](size_t elems) {
    __bf16* p = (__bf16*)(ws + off);
    off += elems * sizeof(__bf16);
    return p;
  };
  __bf16* Wqkvt = alloc((size_t)QKVN * CDIM);   // Wq^T|Wk^T|Wv^T
  __bf16* Wot   = alloc((size_t)CDIM * CDIM);
  __bf16* W1t   = alloc((size_t)CDIM * NMLP);
  __bf16* W2t   = alloc((size_t)CDIM * NMLP);
  __bf16* qkvb  = alloc((size_t)SEQ * QKVN);    // fused q|k|v; later x1|h2
  __bf16* hb    = alloc((size_t)SEQ * CDIM);    // ln1 out / attn out
  __bf16* mb    = alloc((size_t)SEQ * NMLP);    // mlp hidden; head = Vt
  __bf16* pb    = alloc(20480);                 // packed params
  off = (off + 15) & ~(size_t)15;
  float* pscr = (float*)(ws + off);             // O-partials / split-K partials
  off += (size_t)2 * SEQ * CDIM * sizeof(float);
  float* mlb = (float*)(ws + off);              // attn (m,l): 2 x 20 x 1500 x 2
  off += (size_t)2 * NHEAD * SEQ * 2 * sizeof(float);
  int* flag = (int*)(ws + off);

  __bf16* vtb  = mb;                         // Vt[CDIM][VTLD] (dead before MLP1)
  __bf16* x1b  = qkvb;                       // x1 (qkv dead after attention)
  __bf16* h2b  = qkvb + (size_t)SEQ * CDIM;  // ln2 out

  __bf16* qkvbias = pb + 0;
  __bf16* bo_b  = pb + 3840;
  __bf16* g1_b  = pb + 5120;
  __bf16* be1_b = pb + 6400;
  __bf16* g2_b  = pb + 7680;
  __bf16* be2_b = pb + 8960;
  __bf16* b1_b  = pb + 10240;
  __bf16* b2_b  = pb + 15360;

  // 1. pack params (self-detect dtype; writes flag)
  pack_params_kernel<<<65, 256, 0, stream>>>(
      (const unsigned int*)x, bq, bv, bo, g1, be1, g2, be2, bm1, bm2, pb, flag);
  // 2. all weight transposes in one launch
  transpose_all_kernel<<<19200, dim3(32, 8), 0, stream>>>(
      Wq, Wk, Wv, Wo, W1, W2, Wqkvt, Wot, W1t, W2t, flag);
  // 3. h = LN1(x)
  ln_kernel<<<SEQ, 256, 0, stream>>>(x, g1_b, be1_b, hb, flag);
  // 4. qkv = h @ Wqkv^T + (bq|0|bv)   [1500][3840], B-global GEMM, 360 blocks
  gemmbg_kernel<<<360, 256, 0, stream>>>(
      hb, Wqkvt, qkvbias, qkvb, SEQ, QKVN, CDIM, 0, 24);
  // 5. Vt = V^T
  transpose_act_kernel<<<dim3(40, 47), dim3(32, 8), 0, stream>>>(
      qkvb + 2560, vtb, QKVN);
  // 6. attention split-KV partials
  attn_mfma_kernel<<<dim3(24, NHEAD, 2), 256, 0, stream>>>(
      qkvb, qkvb + 1280, vtb, pscr, mlb, QKVN);
  // 7. combine -> hb
  attn_combine_kernel<<<7500, 256, 0, stream>>>(pscr, mlb, hb);
  // 8. attn @ Wo (split-K=2, fp32 partials), 480 blocks
  gemm64_kernel<<<dim3(24, 10, 2), 256, 0, stream>>>(
      hb, Wot, nullptr, pscr, SEQ, CDIM, CDIM, 640, 0, 2);
  // 9. fused: x1 = x + partials + bo ; h2 = LN2(x1)
  resid_ln_kernel<<<SEQ, 256, 0, stream>>>(pscr, bo_b, x, g2_b, be2_b,
                                           x1b, h2b, flag);
  // 10. m = gelu(h2 @ W1 + b1)  (B-global GEMM, 480 blocks)
  gemmbg_kernel<<<480, 256, 0, stream>>>(
      h2b, W1t, b1_b, mb, SEQ, NMLP, CDIM, 1, 24);
  // 11. m @ W2 (split-K=2), 480 blocks
  gemm64_kernel<<<dim3(24, 10, 2), 256, 0, stream>>>(
      mb, W2t, nullptr, pscr, SEQ, CDIM, NMLP, 2560, 0, 2);
  // 12. out = x1 + partials + b2 (output dtype per flag)
  reduce_kernel<<<7500, 256, 0, stream>>>(pscr, b2_b, x1b, d_out,
                                          SEQ * CDIM, CDIM, flag);
}

// Round 5
// 361.562 us; speedup vs baseline: 1.2723x; 1.1213x over previous
//
#include <hip/hip_runtime.h>
#include <hip/hip_bf16.h>
#include <math.h>

typedef __bf16 bf16x8 __attribute__((ext_vector_type(8)));
typedef float f32x4 __attribute__((ext_vector_type(4)));

#define SEQ 1500
#define CDIM 1280
#define NHEAD 20
#define DHEAD 64
#define NMLP 5120
#define QKVN 3840
#define VTLD 1504   // leading dim of transposed V (47*32)
#define APAD 68     // attention LDS stride

#define GLOAD_LDS16(gp, lp)                                                    \
  __builtin_amdgcn_global_load_lds(                                            \
      (const __attribute__((address_space(1))) unsigned int*)(gp),             \
      (__attribute__((address_space(3))) unsigned int*)(lp), 16, 0, 0)

// ---------------- pack params; each block self-detects dtype ----------------
// layout: [0,3840) qkvbias (bq|0|bv) | 3840 bo | 5120 g1 | 6400 be1 |
//         7680 g2 | 8960 be2 | 10240 b1(5120) | 15360 b2
__global__ __launch_bounds__(256) void pack_params_kernel(
    const unsigned int* __restrict__ xw, const void* bq, const void* bv,
    const void* bo, const void* g1, const void* be1, const void* g2,
    const void* be2, const void* b1, const void* b2,
    __bf16* __restrict__ pb, int* __restrict__ flag) {
  __shared__ int cnt[256];
  const unsigned int w = xw[threadIdx.x];
  const unsigned int e = (w >> 7) & 0xFF;
  cnt[threadIdx.x] = (e >= 100 && e <= 150) ? 1 : 0;
  __syncthreads();
  for (int s = 128; s > 0; s >>= 1) {
    if (threadIdx.x < (unsigned)s) cnt[threadIdx.x] += cnt[threadIdx.x + s];
    __syncthreads();
  }
  const int isbf = (cnt[0] >= 160) ? 1 : 0;
  if (blockIdx.x == 0 && threadIdx.x == 0) flag[0] = isbf;
  const int i = blockIdx.x * 256 + threadIdx.x;
  if (i >= 16640) return;
  auto ld = [&](const void* p, int j) -> float {
    return isbf ? (float)((const __bf16*)p)[j] : ((const float*)p)[j];
  };
  float v;
  if (i < 3840) {
    if (i < 1280) v = ld(bq, i);
    else if (i < 2560) v = 0.f;
    else v = ld(bv, i - 2560);
  } else if (i < 5120) v = ld(bo, i - 3840);
  else if (i < 6400) v = ld(g1, i - 5120);
  else if (i < 7680) v = ld(be1, i - 6400);
  else if (i < 8960) v = ld(g2, i - 7680);
  else if (i < 10240) v = ld(be2, i - 8960);
  else if (i < 15360) v = ld(b1, i - 10240);
  else v = ld(b2, i - 15360);
  pb[i] = (__bf16)v;
}

// ---------------- fused weight transpose: all 6 weights, one launch --------
__device__ __forceinline__ void transpose_body(const void* in, __bf16* out,
                                               int K, int N, int isbf,
                                               int bx, int by) {
  __shared__ __bf16 t[32][33];
  const int tx = threadIdx.x, ty = threadIdx.y;
  const int n0 = bx * 32, k0 = by * 32;
  if (isbf) {
    const __bf16* s = (const __bf16*)in;
#pragma unroll
    for (int i = ty; i < 32; i += 8)
      t[i][tx] = s[(size_t)(k0 + i) * N + n0 + tx];
  } else {
    const float* s = (const float*)in;
#pragma unroll
    for (int i = ty; i < 32; i += 8)
      t[i][tx] = (__bf16)s[(size_t)(k0 + i) * N + n0 + tx];
  }
  __syncthreads();
#pragma unroll
  for (int i = ty; i < 32; i += 8)
    out[(size_t)(n0 + i) * K + k0 + tx] = t[tx][i];
}

__global__ __launch_bounds__(256) void transpose_all_kernel(
    const void* Wq, const void* Wk, const void* Wv, const void* Wo,
    const void* W1, const void* W2, __bf16* __restrict__ Wqkvt,
    __bf16* __restrict__ Wot, __bf16* __restrict__ W1t,
    __bf16* __restrict__ W2t, const int* __restrict__ flag) {
  const int id = blockIdx.x;
  const int isbf = flag[0];
  if (id < 6400) {                      // Wq|Wk|Wv|Wo : 4 x (40x40)
    const int w = id / 1600, r = id % 1600;
    const void* in = (w == 0) ? Wq : (w == 1) ? Wk : (w == 2) ? Wv : Wo;
    __bf16* out = (w < 3) ? (Wqkvt + (size_t)w * CDIM * CDIM) : Wot;
    transpose_body(in, out, CDIM, CDIM, isbf, r % 40, r / 40);
  } else if (id < 12800) {              // W1 : 160x40
    const int r = id - 6400;
    transpose_body(W1, W1t, CDIM, NMLP, isbf, r % 160, r / 160);
  } else {                              // W2 : 40x160
    const int r = id - 12800;
    transpose_body(W2, W2t, NMLP, CDIM, isbf, r % 40, r / 40);
  }
}

// ---------------- activation transpose: [SEQ][.] -> [N][VTLD] --------------
__global__ __launch_bounds__(256) void transpose_act_kernel(const __bf16* __restrict__ in,
                                                            __bf16* __restrict__ out,
                                                            int istride) {
  __shared__ __bf16 t[32][33];
  const int tx = threadIdx.x, ty = threadIdx.y;
  const int n0 = blockIdx.x * 32, k0 = blockIdx.y * 32;
#pragma unroll
  for (int i = ty; i < 32; i += 8) {
    const int k = k0 + i;
    t[i][tx] = (k < SEQ) ? in[(size_t)k * istride + n0 + tx] : (__bf16)0.f;
  }
  __syncthreads();
#pragma unroll
  for (int i = ty; i < 32; i += 8) {
    const int kk = k0 + tx;
    if (kk < VTLD) out[(size_t)(n0 + i) * VTLD + kk] = t[tx][i];
  }
}

// ---------------- layernorm 1 (row-major out); X dtype per flag ------------
__global__ __launch_bounds__(256) void ln_kernel(const void* __restrict__ X,
                                                 const __bf16* __restrict__ gamma,
                                                 const __bf16* __restrict__ beta,
                                                 __bf16* __restrict__ Y,
                                                 const int* __restrict__ flag) {
  const int isf32 = (flag[0] == 0);
  const int row = blockIdx.x;
  float v[5];
  float s = 0.f, s2 = 0.f;
#pragma unroll
  for (int i = 0; i < 5; ++i) {
    const int c = threadIdx.x + 256 * i;
    const size_t idx = (size_t)row * CDIM + c;
    v[i] = isf32 ? ((const float*)X)[idx] : (float)((const __bf16*)X)[idx];
    s += v[i];
    s2 += v[i] * v[i];
  }
  const int lane = threadIdx.x & 63, wv = threadIdx.x >> 6;
#pragma unroll
  for (int off = 32; off > 0; off >>= 1) {
    s += __shfl_down(s, off);
    s2 += __shfl_down(s2, off);
  }
  __shared__ float red[8];
  if (lane == 0) { red[wv] = s; red[4 + wv] = s2; }
  __syncthreads();
  s = red[0] + red[1] + red[2] + red[3];
  s2 = red[4] + red[5] + red[6] + red[7];
  const float mu = s * (1.f / CDIM);
  const float var = s2 * (1.f / CDIM) - mu * mu;
  const float rstd = rsqrtf(fmaxf(var, 0.f) + 1e-5f);
#pragma unroll
  for (int i = 0; i < 5; ++i) {
    const int c = threadIdx.x + 256 * i;
    Y[(size_t)row * CDIM + c] =
        (__bf16)((v[i] - mu) * rstd * (float)gamma[c] + (float)beta[c]);
  }
}

// ---------------- fused: x1 = x + sum(P) + bo ; h2 = LN2(x1) ----------------
__global__ __launch_bounds__(256) void resid_ln_kernel(
    const float* __restrict__ P, const __bf16* __restrict__ bo,
    const void* __restrict__ X, const __bf16* __restrict__ gamma,
    const __bf16* __restrict__ beta, __bf16* __restrict__ X1,
    __bf16* __restrict__ H2, const int* __restrict__ flag) {
  const int isf32 = (flag[0] == 0);
  const int row = blockIdx.x;
  const int MN = SEQ * CDIM;
  float v[5];
  float s = 0.f, s2 = 0.f;
#pragma unroll
  for (int i = 0; i < 5; ++i) {
    const int c = threadIdx.x + 256 * i;
    const size_t idx = (size_t)row * CDIM + c;
    const float xv = isf32 ? ((const float*)X)[idx] : (float)((const __bf16*)X)[idx];
    const float val = P[idx] + P[MN + idx] + (float)bo[c] + xv;
    X1[idx] = (__bf16)val;
    v[i] = val;
    s += val;
    s2 += val * val;
  }
  const int lane = threadIdx.x & 63, wv = threadIdx.x >> 6;
#pragma unroll
  for (int off = 32; off > 0; off >>= 1) {
    s += __shfl_down(s, off);
    s2 += __shfl_down(s2, off);
  }
  __shared__ float red[8];
  if (lane == 0) { red[wv] = s; red[4 + wv] = s2; }
  __syncthreads();
  s = red[0] + red[1] + red[2] + red[3];
  s2 = red[4] + red[5] + red[6] + red[7];
  const float mu = s * (1.f / CDIM);
  const float var = s2 * (1.f / CDIM) - mu * mu;
  const float rstd = rsqrtf(fmaxf(var, 0.f) + 1e-5f);
#pragma unroll
  for (int i = 0; i < 5; ++i) {
    const int c = threadIdx.x + 256 * i;
    H2[(size_t)row * CDIM + c] =
        (__bf16)((v[i] - mu) * rstd * (float)gamma[c] + (float)beta[c]);
  }
}

// ---------------- GEMM 64x128 tile, BK=64 (2 x 32 chunks), 2-barrier -------
// (R5 structure, proven). nsplit>1: fp32 partials. Used for Wo / MLP2.
__global__ __launch_bounds__(256) void gemm64_kernel(
    const __bf16* __restrict__ A, const __bf16* __restrict__ Bt,
    const __bf16* __restrict__ bias, void* __restrict__ Cv,
    int M, int N, int K, int KS, int gelu, int nsplit) {
  __shared__ __bf16 As[2][64 * 32];
  __shared__ __bf16 Bs[2][128 * 32];
  const int bm = blockIdx.x, bn = blockIdx.y, sz = blockIdx.z;
  const int tid = threadIdx.x;
  const int lane = tid & 63, wave = tid >> 6;
  const int l16 = lane & 15, kq = (lane >> 4) << 3;
  const int lrow = lane >> 2, lcol = (lane & 3) << 3;
  const int wn = wave * 32;

  f32x4 acc[4][2];
  const f32x4 zero = {0.f, 0.f, 0.f, 0.f};
#pragma unroll
  for (int i = 0; i < 4; ++i)
#pragma unroll
    for (int j = 0; j < 2; ++j) acc[i][j] = zero;

  const int kbeg = sz * KS;
  int kend = kbeg + KS;
  if (kend > K) kend = K;

  int ga = bm * 64 + wave * 16 + lrow;
  if (ga > M - 1) ga = M - 1;  // clamp: garbage rows never stored
  const __bf16* Ap = A + (size_t)ga * K + lcol;

  for (int k0 = kbeg; k0 < kend; k0 += 64) {
#pragma unroll
    for (int c = 0; c < 2; ++c)
      GLOAD_LDS16(Ap + k0 + c * 32, &As[c][wave * 512]);
#pragma unroll
    for (int c = 0; c < 2; ++c)
#pragma unroll
      for (int t = 0; t < 2; ++t) {
        const int seg = t * 4 + wave;
        const int gb = bn * 128 + seg * 16 + lrow;  // N multiple of 128
        GLOAD_LDS16(Bt + (size_t)gb * K + k0 + c * 32 + lcol, &Bs[c][seg * 512]);
      }
    __syncthreads();
    bf16x8 af[4][2], bfr[2][2];
#pragma unroll
    for (int i = 0; i < 4; ++i)
#pragma unroll
      for (int c = 0; c < 2; ++c)
        af[i][c] = *(const bf16x8*)(&As[c][(i * 16 + l16) * 32 + kq]);
#pragma unroll
    for (int j = 0; j < 2; ++j)
#pragma unroll
      for (int c = 0; c < 2; ++c)
        bfr[j][c] = *(const bf16x8*)(&Bs[c][(wn + j * 16 + l16) * 32 + kq]);
#pragma unroll
    for (int i = 0; i < 4; ++i)
#pragma unroll
      for (int j = 0; j < 2; ++j)
#pragma unroll
        for (int c = 0; c < 2; ++c)
          acc[i][j] = __builtin_amdgcn_mfma_f32_16x16x32_bf16(af[i][c], bfr[j][c],
                                                              acc[i][j], 0, 0, 0);
    __syncthreads();
  }

  const int rq4 = (lane >> 4) * 4;
  if (nsplit > 1) {
    float* P = (float*)Cv + (size_t)sz * M * N;
#pragma unroll
    for (int i = 0; i < 4; ++i)
#pragma unroll
      for (int r = 0; r < 4; ++r) {
        const int grow = bm * 64 + i * 16 + rq4 + r;
        if (grow >= M) continue;
#pragma unroll
        for (int j = 0; j < 2; ++j) {
          const int gcol = bn * 128 + wn + j * 16 + l16;
          P[(size_t)grow * N + gcol] = acc[i][j][r];
        }
      }
  } else {
    __bf16* Cb = (__bf16*)Cv;
#pragma unroll
    for (int i = 0; i < 4; ++i)
#pragma unroll
      for (int r = 0; r < 4; ++r) {
        const int grow = bm * 64 + i * 16 + rq4 + r;
        if (grow >= M) continue;
#pragma unroll
        for (int j = 0; j < 2; ++j) {
          const int gcol = bn * 128 + wn + j * 16 + l16;
          float vv = acc[i][j][r];
          if (bias) vv += (float)bias[gcol];
          if (gelu) vv = 0.5f * vv * (1.f + erff(vv * 0.70710678118654752f));
          Cb[(size_t)grow * N + gcol] = (__bf16)vv;
        }
      }
  }
}

// ---------------- GEMM 128x128, BK=64, counted-vmcnt dbuf (T3/T4 minimum) --
// Same tile/wave geometry as the proven gemm128s, but: stage issued at TOP of
// the iteration, s_waitcnt vmcnt(8) waits only the OLDER tile (full-K-tile
// cover; never drains mid-loop), raw s_barrier pair, setprio(1) around MFMA,
// R1-verified XOR-swizzle staging/read pair (bank conflicts ~0).
// 64 KiB LDS -> 2 blocks/CU.  N % 128 == 0, K % 64 == 0, K/64 >= 2.
__global__ __launch_bounds__(256, 2) void gemm128c_kernel(
    const __bf16* __restrict__ A, const __bf16* __restrict__ Bt,
    const __bf16* __restrict__ bias, __bf16* __restrict__ C,
    int M, int N, int K, int gelu, int mtiles) {
  __shared__ __bf16 As[2][128 * 64];   // 16 KiB per buf
  __shared__ __bf16 Bs[2][128 * 64];

  // bijective XCD swizzle (m204)
  const int nwg = mtiles * (N >> 7);
  const int qq = nwg >> 3, rr = nwg & 7;
  const int xcd = blockIdx.x & 7, rk = blockIdx.x >> 3;
  const int wg = (xcd < rr ? xcd * (qq + 1) : rr * (qq + 1) + (xcd - rr) * qq) + rk;
  const int bm = wg % mtiles, bn = wg / mtiles;

  const int tid = threadIdx.x;
  const int lane = tid & 63, wave = tid >> 6;
  const int wm = (wave >> 1) * 64, wn = (wave & 1) * 64;   // 2x2 wave grid
  const int l16 = lane & 15, quad = lane >> 4;

  // staging: 4 sets of 32 rows x 64 k for each of A and B.
  // linear LDS dest + inverse-swizzled global source (rule 21; R1-verified).
  const int rT = tid >> 3, sl = tid & 7;
  const int aoff = ((sl * 16) ^ ((rT & 7) << 4)) >> 1;     // elems
  const __bf16* Ap[4];
  const __bf16* Bp[4];
#pragma unroll
  for (int s = 0; s < 4; ++s) {
    int gm = bm * 128 + s * 32 + rT;
    if (gm > M - 1) gm = M - 1;      // clamp: garbage rows never stored
    Ap[s] = A + (size_t)gm * K + aoff;
    Bp[s] = Bt + (size_t)(bn * 128 + s * 32 + rT) * K + aoff;
  }
  const int ldst = tid * 8;

  // swizzled ds_read k-offsets (elems); read-row & 7 == l16 & 7 always
  const int xsw = (l16 & 7) << 4;
  const int kb0 = ((quad << 4) ^ xsw) >> 1;
  const int kb1 = (((quad << 4) + 64) ^ xsw) >> 1;

  f32x4 acc[4][4];
  const f32x4 zero = {0.f, 0.f, 0.f, 0.f};
#pragma unroll
  for (int i = 0; i < 4; ++i)
#pragma unroll
    for (int j = 0; j < 4; ++j) acc[i][j] = zero;

  const int NT = K >> 6;

#define STAGE128(b, k0)                                       \
  do {                                                        \
    _Pragma("unroll")                                         \
    for (int s = 0; s < 4; ++s) {                             \
      GLOAD_LDS16(Ap[s] + (k0), &As[b][s * 2048 + ldst]);     \
      GLOAD_LDS16(Bp[s] + (k0), &Bs[b][s * 2048 + ldst]);     \
    }                                                         \
  } while (0)

  STAGE128(0, 0);
  for (int t = 0; t < NT; ++t) {
    const int cur = t & 1;
    if (t + 1 < NT) {
      STAGE128(cur ^ 1, (t + 1) * 64);
      // 16 outstanding; wait the oldest 8 (= buf cur). Cover for the 8 just
      // issued = this whole iteration. Never drains to 0 in steady state.
      asm volatile("s_waitcnt vmcnt(8)" ::: "memory");
    } else {
      asm volatile("s_waitcnt vmcnt(0)" ::: "memory");
    }
    __builtin_amdgcn_s_barrier();          // all waves' buf-cur loads done
    __builtin_amdgcn_sched_barrier(0);
    bf16x8 af[4][2], bfr[4][2];
#pragma unroll
    for (int i = 0; i < 4; ++i) {
      const int row = (wm + i * 16 + l16) * 64;
      af[i][0] = *(const bf16x8*)(&As[cur][row + kb0]);
      af[i][1] = *(const bf16x8*)(&As[cur][row + kb1]);
    }
#pragma unroll
    for (int j = 0; j < 4; ++j) {
      const int row = (wn + j * 16 + l16) * 64;
      bfr[j][0] = *(const bf16x8*)(&Bs[cur][row + kb0]);
      bfr[j][1] = *(const bf16x8*)(&Bs[cur][row + kb1]);
    }
    __builtin_amdgcn_s_setprio(1);
#pragma unroll
    for (int i = 0; i < 4; ++i)
#pragma unroll
      for (int j = 0; j < 4; ++j)
#pragma unroll
        for (int c = 0; c < 2; ++c)
          acc[i][j] = __builtin_amdgcn_mfma_f32_16x16x32_bf16(af[i][c], bfr[j][c],
                                                              acc[i][j], 0, 0, 0);
    __builtin_amdgcn_s_setprio(0);
    __builtin_amdgcn_s_barrier();          // reads of buf cur done -> next
    __builtin_amdgcn_sched_barrier(0);     // iter may overwrite cur^1 safely
  }
#undef STAGE128

  // ----- epilogue -----
#pragma unroll
  for (int i = 0; i < 4; ++i)
#pragma unroll
    for (int r = 0; r < 4; ++r) {
      const int grow = bm * 128 + wm + i * 16 + quad * 4 + r;
      if (grow >= M) continue;
#pragma unroll
      for (int j = 0; j < 4; ++j) {
        const int gcol = bn * 128 + wn + j * 16 + l16;
        float vv = acc[i][j][r];
        if (bias) vv += (float)bias[gcol];
        if (gelu) vv = 0.5f * vv * (1.f + erff(vv * 0.70710678118654752f));
        C[(size_t)grow * N + gcol] = (__bf16)vv;
      }
    }
}

// ---------------- final reduce: out = resid + sum(P) + bias ----------------
__global__ __launch_bounds__(256) void reduce_kernel(
    const float* __restrict__ P, const __bf16* __restrict__ bias,
    const __bf16* __restrict__ resid, void* __restrict__ out,
    int MN, int N, const int* __restrict__ flag) {
  const int i = blockIdx.x * 256 + threadIdx.x;
  if (i >= MN) return;
  const float v = P[i] + P[(size_t)MN + i] + (float)bias[i % N] + (float)resid[i];
  if (flag[0]) ((__bf16*)out)[i] = (__bf16)v;
  else         ((float*)out)[i] = v;
}

// ---------------- MFMA flash attention, split-KV ---------------------------
__global__ __launch_bounds__(256) void attn_mfma_kernel(
    const __bf16* __restrict__ Q,    // fused base (+0), row stride rs
    const __bf16* __restrict__ Kk,   // fused base + 1280, row stride rs
    const __bf16* __restrict__ Vt,   // [CDIM][VTLD]
    float* __restrict__ Opart,       // [2][SEQ][CDIM]
    float* __restrict__ ml,          // [2][NHEAD][SEQ][2]
    int rs) {
  const int h = blockIdx.y;
  const int q0 = blockIdx.x * 64;
  const int z = blockIdx.z;
  const int tid = threadIdx.x;
  const int wave = tid >> 6, lane = tid & 63;
  const int l16 = lane & 15, quad = lane >> 4;

  __shared__ __bf16 Ks[64 * APAD];
  __shared__ __bf16 Vs[64 * APAD];
  __shared__ __bf16 Ps[4][16 * APAD];

  bf16x8 qf[2];
  {
    int q = q0 + wave * 16 + l16;
    if (q > SEQ - 1) q = SEQ - 1;
    const __bf16* qp = Q + (size_t)q * rs + h * DHEAD + quad * 8;
    qf[0] = *(const bf16x8*)(qp);
    qf[1] = *(const bf16x8*)(qp + 32);
  }

  f32x4 oacc[4];
  const f32x4 zero = {0.f, 0.f, 0.f, 0.f};
#pragma unroll
  for (int jt = 0; jt < 4; ++jt) oacc[jt] = zero;
  float mrow[4], lrow[4];
#pragma unroll
  for (int r = 0; r < 4; ++r) { mrow[r] = -30000.f; lrow[r] = 0.f; }

  const int srow = tid >> 2;
  const int scol = (tid & 3) << 4;

  const __bf16* Kbase = Kk + h * DHEAD;
  const __bf16* Vbase = Vt + (size_t)(h * DHEAD + srow) * VTLD;

  for (int kt = z * 12; kt < z * 12 + 12; ++kt) {
    const int key0 = kt * 64;
    __syncthreads();
    {
      int gk = key0 + srow;
      if (gk > SEQ - 1) gk = SEQ - 1;
      const __bf16* kp = Kbase + (size_t)gk * rs + scol;
      *(bf16x8*)(&Ks[srow * APAD + scol]) = *(const bf16x8*)(kp);
      *(bf16x8*)(&Ks[srow * APAD + scol + 8]) = *(const bf16x8*)(kp + 8);
      const __bf16* vp = Vbase + key0 + scol;
      *(bf16x8*)(&Vs[srow * APAD + scol]) = *(const bf16x8*)(vp);
      *(bf16x8*)(&Vs[srow * APAD + scol + 8]) = *(const bf16x8*)(vp + 8);
    }
    __syncthreads();

    f32x4 s[4];
#pragma unroll
    for (int jt = 0; jt < 4; ++jt) s[jt] = zero;
#pragma unroll
    for (int jt = 0; jt < 4; ++jt)
#pragma unroll
      for (int ks = 0; ks < 2; ++ks) {
        const bf16x8 kf = *(const bf16x8*)(&Ks[(jt * 16 + l16) * APAD + ks * 32 + quad * 8]);
        s[jt] = __builtin_amdgcn_mfma_f32_16x16x32_bf16(qf[ks], kf, s[jt], 0, 0, 0);
      }

#pragma unroll
    for (int jt = 0; jt < 4; ++jt) {
      const int key = key0 + jt * 16 + l16;
#pragma unroll
      for (int r = 0; r < 4; ++r) {
        float sv = s[jt][r] * 0.125f;
        if (key >= SEQ) sv = -30000.f;
        s[jt][r] = sv;
      }
    }

#pragma unroll
    for (int r = 0; r < 4; ++r) {
      float tmax = fmaxf(fmaxf(s[0][r], s[1][r]), fmaxf(s[2][r], s[3][r]));
#pragma unroll
      for (int off = 8; off > 0; off >>= 1) tmax = fmaxf(tmax, __shfl_xor(tmax, off));
      const float mnew = fmaxf(mrow[r], tmax);
      const float alpha = __expf(mrow[r] - mnew);
      mrow[r] = mnew;
      lrow[r] *= alpha;
#pragma unroll
      for (int jt = 0; jt < 4; ++jt) oacc[jt][r] *= alpha;
#pragma unroll
      for (int jt = 0; jt < 4; ++jt) {
        const float p = __expf(s[jt][r] - mnew);
        lrow[r] += p;
        Ps[wave][(quad * 4 + r) * APAD + jt * 16 + l16] = (__bf16)p;
      }
    }

    bf16x8 pf[2];
    pf[0] = *(const bf16x8*)(&Ps[wave][l16 * APAD + quad * 8]);
    pf[1] = *(const bf16x8*)(&Ps[wave][l16 * APAD + 32 + quad * 8]);
#pragma unroll
    for (int jt = 0; jt < 4; ++jt)
#pragma unroll
      for (int ks = 0; ks < 2; ++ks) {
        const bf16x8 vf = *(const bf16x8*)(&Vs[(jt * 16 + l16) * APAD + ks * 32 + quad * 8]);
        oacc[jt] = __builtin_amdgcn_mfma_f32_16x16x32_bf16(pf[ks], vf, oacc[jt], 0, 0, 0);
      }
  }

  float* Oz = Opart + (size_t)z * SEQ * CDIM;
#pragma unroll
  for (int r = 0; r < 4; ++r) {
    float lt = lrow[r];
#pragma unroll
    for (int off = 8; off > 0; off >>= 1) lt += __shfl_xor(lt, off);
    const int q = q0 + wave * 16 + quad * 4 + r;
    if (q < SEQ) {
#pragma unroll
      for (int jt = 0; jt < 4; ++jt)
        Oz[(size_t)q * CDIM + h * DHEAD + jt * 16 + l16] = oacc[jt][r];
      if (l16 == 0) {
        const size_t mi = ((size_t)(z * NHEAD + h) * SEQ + q) * 2;
        ml[mi] = mrow[r];
        ml[mi + 1] = lt;
      }
    }
  }
}

// ---------------- combine the two kv-halves --------------------------------
__global__ __launch_bounds__(256) void attn_combine_kernel(
    const float* __restrict__ Op, const float* __restrict__ ml,
    __bf16* __restrict__ O) {
  const int i = blockIdx.x * 256 + threadIdx.x;
  if (i >= SEQ * CDIM) return;
  const int q = i / CDIM;
  const int h = (i % CDIM) >> 6;
  const size_t m1i = ((size_t)h * SEQ + q) * 2;
  const size_t m2i = ((size_t)(NHEAD + h) * SEQ + q) * 2;
  const float m1 = ml[m1i], l1 = ml[m1i + 1];
  const float m2 = ml[m2i], l2 = ml[m2i + 1];
  const float M = fmaxf(m1, m2);
  const float e1 = __expf(m1 - M), e2 = __expf(m2 - M);
  const float v = (e1 * Op[i] + e2 * Op[(size_t)SEQ * CDIM + i]) /
                  (e1 * l1 + e2 * l2);
  O[i] = (__bf16)v;
}

// ---------------- launch ----------------
extern "C" void kernel_launch(void* const* d_in, const int* in_sizes, int n_in,
                              void* d_out, int out_size, void* d_ws, size_t ws_size,
                              hipStream_t stream) {
  const void* x   = d_in[0];
  const void* Wq  = d_in[1];
  const void* bq  = d_in[2];
  const void* Wk  = d_in[3];
  const void* Wv  = d_in[4];
  const void* bv  = d_in[5];
  const void* Wo  = d_in[6];
  const void* bo  = d_in[7];
  const void* g1  = d_in[8];
  const void* be1 = d_in[9];
  const void* g2  = d_in[10];
  const void* be2 = d_in[11];
  const void* W1  = d_in[12];
  const void* bm1 = d_in[13];
  const void* W2  = d_in[14];
  const void* bm2 = d_in[15];

  char* ws = (char*)d_ws;
  size_t off = 0;
  auto alloc = [&](size_t elems) {
    __bf16* p = (__bf16*)(ws + off);
    off += elems * sizeof(__bf16);
    return p;
  };
  __bf16* Wqkvt = alloc((size_t)QKVN * CDIM);   // Wq^T|Wk^T|Wv^T
  __bf16* Wot   = alloc((size_t)CDIM * CDIM);
  __bf16* W1t   = alloc((size_t)CDIM * NMLP);
  __bf16* W2t   = alloc((size_t)CDIM * NMLP);
  __bf16* qkvb  = alloc((size_t)SEQ * QKVN);    // fused q|k|v; later x1|h2
  __bf16* hb    = alloc((size_t)SEQ * CDIM);    // ln1 out / attn out
  __bf16* mb    = alloc((size_t)SEQ * NMLP);    // mlp hidden; head = Vt
  __bf16* pb    = alloc(20480);                 // packed params
  off = (off + 15) & ~(size_t)15;
  float* pscr = (float*)(ws + off);             // O-partials / split-K partials
  off += (size_t)2 * SEQ * CDIM * sizeof(float);
  float* mlb = (float*)(ws + off);              // attn (m,l): 2 x 20 x 1500 x 2
  off += (size_t)2 * NHEAD * SEQ * 2 * sizeof(float);
  int* flag = (int*)(ws + off);

  __bf16* vtb  = mb;                         // Vt[CDIM][VTLD] (dead before MLP1)
  __bf16* x1b  = qkvb;                       // x1 (qkv dead after attention)
  __bf16* h2b  = qkvb + (size_t)SEQ * CDIM;  // ln2 out

  __bf16* qkvbias = pb + 0;
  __bf16* bo_b  = pb + 3840;
  __bf16* g1_b  = pb + 5120;
  __bf16* be1_b = pb + 6400;
  __bf16* g2_b  = pb + 7680;
  __bf16* be2_b = pb + 8960;
  __bf16* b1_b  = pb + 10240;
  __bf16* b2_b  = pb + 15360;

  // 1. pack params (self-detect dtype; writes flag)
  pack_params_kernel<<<65, 256, 0, stream>>>(
      (const unsigned int*)x, bq, bv, bo, g1, be1, g2, be2, bm1, bm2, pb, flag);
  // 2. all weight transposes in one launch
  transpose_all_kernel<<<19200, dim3(32, 8), 0, stream>>>(
      Wq, Wk, Wv, Wo, W1, W2, Wqkvt, Wot, W1t, W2t, flag);
  // 3. h = LN1(x)
  ln_kernel<<<SEQ, 256, 0, stream>>>(x, g1_b, be1_b, hb, flag);
  // 4. qkv = h @ Wqkv^T + (bq|0|bv)  [1500][3840], counted-vmcnt 128^2, 360 blk
  gemm128c_kernel<<<360, 256, 0, stream>>>(
      hb, Wqkvt, qkvbias, qkvb, SEQ, QKVN, CDIM, 0, 12);
  // 5. Vt = V^T
  transpose_act_kernel<<<dim3(40, 47), dim3(32, 8), 0, stream>>>(
      qkvb + 2560, vtb, QKVN);
  // 6. attention split-KV partials
  attn_mfma_kernel<<<dim3(24, NHEAD, 2), 256, 0, stream>>>(
      qkvb, qkvb + 1280, vtb, pscr, mlb, QKVN);
  // 7. combine -> hb
  attn_combine_kernel<<<7500, 256, 0, stream>>>(pscr, mlb, hb);
  // 8. attn @ Wo (split-K=2, fp32 partials), 480 blocks
  gemm64_kernel<<<dim3(24, 10, 2), 256, 0, stream>>>(
      hb, Wot, nullptr, pscr, SEQ, CDIM, CDIM, 640, 0, 2);
  // 9. fused: x1 = x + partials + bo ; h2 = LN2(x1)
  resid_ln_kernel<<<SEQ, 256, 0, stream>>>(pscr, bo_b, x, g2_b, be2_b,
                                           x1b, h2b, flag);
  // 10. m = gelu(h2 @ W1 + b1)  (counted-vmcnt 128^2, 480 blocks)
  gemm128c_kernel<<<480, 256, 0, stream>>>(
      h2b, W1t, b1_b, mb, SEQ, NMLP, CDIM, 1, 12);
  // 11. m @ W2 (split-K=2), 480 blocks
  gemm64_kernel<<<dim3(24, 10, 2), 256, 0, stream>>>(
      mb, W2t, nullptr, pscr, SEQ, CDIM, NMLP, 2560, 0, 2);
  // 12. out = x1 + partials + b2 (output dtype per flag)
  reduce_kernel<<<7500, 256, 0, stream>>>(pscr, b2_b, x1b, d_out,
                                          SEQ * CDIM, CDIM, flag);
}